// Round 2
// baseline (765.698 us; speedup 1.0000x reference)
//
#include <hip/hip_runtime.h>
#include <math.h>

#define HH 100
#define BB 64
#define SS 384
#define IB 8
#define HT 10
#define NT 10
#define EPSF 1e-6f

// ---------------- Kernel 1: per-(dir,l,b,j) w2-weighted q-norms + plain q-norms ----------------
__global__ __launch_bounds__(256) void qnorm_kernel(
    const float* __restrict__ qf, const float* __restrict__ qb,
    const float* __restrict__ w2f, const float* __restrict__ w2b,
    float* __restrict__ nq2)
{
  int t = blockIdx.x * 256 + threadIdx.x;
  if (t >= 2 * BB * SS) return;
  int dir = t / (BB * SS);
  int rem = t % (BB * SS);
  int b = rem / SS;
  int j = rem % SS;
  const float* q  = dir ? qb  : qf;
  const float* w2 = dir ? w2b : w2f;
  float s0 = 0.f, s1 = 0.f, sp = 0.f;
  for (int h = 0; h < HH; ++h) {
    float qv = q[(size_t)h * BB * SS + (size_t)b * SS + j];
    float w0 = w2[h], w1 = w2[HH + h];
    float q2 = qv * qv;
    s0 = fmaf(w0 * w0, q2, s0);
    s1 = fmaf(w1 * w1, q2, s1);
    sp += q2;
  }
  nq2[((size_t)(dir * 2 + 0) * BB + b) * SS + j] = fmaxf(sqrtf(s0), EPSF);
  nq2[((size_t)(dir * 2 + 1) * BB + b) * SS + j] = fmaxf(sqrtf(s1), EPSF);
  nq2[((size_t)(4 + dir) * BB + b) * SS + j]     = fmaxf(sqrtf(sp), EPSF);
}

// ---------------- Kernel 2: fused main kernel ----------------
__global__ __launch_bounds__(256) void bimpm_kernel(
    const float* __restrict__ pf, const float* __restrict__ pb,
    const float* __restrict__ qf, const float* __restrict__ qb,
    const float* __restrict__ w1f, const float* __restrict__ w1b,
    const float* __restrict__ w2f, const float* __restrict__ w2b,
    const float* __restrict__ w3f_, const float* __restrict__ w4f_,
    const float* __restrict__ nq2ws, float* __restrict__ out)
{
  __shared__ __align__(16) float qt[HT][SS];     // 15360 B
  __shared__ float pcol[IB][HH];                  // 3200 B
  __shared__ float qlast[HH];                     // 400 B
  __shared__ float w1sq[2][HH], w2sq[2][HH], w3sq[2][HH], w4sq[2][HH]; // 3200 B

  const int blk = blockIdx.x;
  const int dir = blk / (BB * (SS / IB));
  const int rem = blk % (BB * (SS / IB));
  const int b   = rem / (SS / IB);
  const int i0  = (rem % (SS / IB)) * IB;

  const float* __restrict__ p  = dir ? pb  : pf;
  const float* __restrict__ q  = dir ? qb  : qf;
  const float* __restrict__ w1 = dir ? w1b : w1f;
  const float* __restrict__ w2 = dir ? w2b : w2f;

  const int t  = threadIdx.x;
  const int il = t >> 5;     // row within i-block (0..7)
  const int jg = t & 31;     // lane group over j (0..31)
  const int i  = i0 + il;
  const int jbase = jg * 12;

  // stage squared weights (w3/w4 always forward — reference quirk)
  if (t < 2 * HH) {
    int l = t / HH, h = t % HH;
    float a;
    a = w1[t];   w1sq[l][h] = a * a;
    a = w2[t];   w2sq[l][h] = a * a;
    a = w3f_[t]; w3sq[l][h] = a * a;
    a = w4f_[t]; w4sq[l][h] = a * a;
  }
  // stage p columns for this i-block: pcol[ii][h]
  for (int e = t; e < IB * HH; e += 256) {
    int h = e / IB, ii = e % IB;
    pcol[ii][h] = p[(size_t)h * BB * SS + (size_t)b * SS + i0 + ii];
  }
  // stage q's last column
  if (t < HH) qlast[t] = q[(size_t)t * BB * SS + (size_t)b * SS + (SS - 1)];

  const float* __restrict__ qrow0 = q + (size_t)b * SS;

  // ---- Pass 1: raw gram / g2(l=0) / g2(l=1) rows in registers ----
  float att[12], ga[12], gb[12];
#pragma unroll
  for (int k = 0; k < 12; ++k) { att[k] = 0.f; ga[k] = 0.f; gb[k] = 0.f; }

  for (int ht = 0; ht < NT; ++ht) {
    const int h0 = ht * HT;
    __syncthreads();
#pragma unroll
    for (int e = 0; e < (HT * SS) / 256; ++e) {  // 15 iters
      int idx = t + e * 256;
      int hh = idx / SS, j = idx % SS;
      qt[hh][j] = qrow0[(size_t)(h0 + hh) * BB * SS + j];
    }
    __syncthreads();
#pragma unroll
    for (int hh = 0; hh < HT; ++hh) {
      const int h = h0 + hh;
      const float pv  = pcol[il][h];
      const float pa  = pv * w2sq[0][h];
      const float pbv = pv * w2sq[1][h];
      const float4* qr = (const float4*)&qt[hh][jbase];
#pragma unroll
      for (int kk = 0; kk < 3; ++kk) {
        float4 qv = qr[kk];
        att[kk*4+0] = fmaf(pv,  qv.x, att[kk*4+0]);
        att[kk*4+1] = fmaf(pv,  qv.y, att[kk*4+1]);
        att[kk*4+2] = fmaf(pv,  qv.z, att[kk*4+2]);
        att[kk*4+3] = fmaf(pv,  qv.w, att[kk*4+3]);
        ga[kk*4+0]  = fmaf(pa,  qv.x, ga[kk*4+0]);
        ga[kk*4+1]  = fmaf(pa,  qv.y, ga[kk*4+1]);
        ga[kk*4+2]  = fmaf(pa,  qv.z, ga[kk*4+2]);
        ga[kk*4+3]  = fmaf(pa,  qv.w, ga[kk*4+3]);
        gb[kk*4+0]  = fmaf(pbv, qv.x, gb[kk*4+0]);
        gb[kk*4+1]  = fmaf(pbv, qv.y, gb[kk*4+1]);
        gb[kk*4+2]  = fmaf(pbv, qv.z, gb[kk*4+2]);
        gb[kk*4+3]  = fmaf(pbv, qv.w, gb[kk*4+3]);
      }
    }
  }

  // ---- Pass 1b: rescale by |q_j| (cosine up to row-constant |p_i|), then row reductions ----
  float rowsum = 0.f;
  float amax = -INFINITY; int aidx = 0;
  float m2a = -INFINITY, m2b = -INFINITY;
  {
    const float* nqa = nq2ws + ((size_t)(dir * 2 + 0) * BB + b) * SS + jbase;
    const float* nqb = nq2ws + ((size_t)(dir * 2 + 1) * BB + b) * SS + jbase;
    const float* nqp = nq2ws + ((size_t)(4 + dir) * BB + b) * SS + jbase;
#pragma unroll
    for (int k = 0; k < 12; ++k) {
      float d = att[k] / nqp[k];   // att cosine * |p_i| ; |p_i| cancels in attn & argmax
      att[k] = d;
      rowsum += d;
      if (d > amax) { amax = d; aidx = jbase + k; }
      m2a = fmaxf(m2a, ga[k] / nqa[k]);
      m2b = fmaxf(m2b, gb[k] / nqb[k]);
    }
  }
#pragma unroll
  for (int m = 1; m < 32; m <<= 1) {
    rowsum += __shfl_xor(rowsum, m, 32);
    float ov = __shfl_xor(amax, m, 32);
    int   oi = __shfl_xor(aidx, m, 32);
    if (ov > amax || (ov == amax && oi < aidx)) { amax = ov; aidx = oi; }
    m2a = fmaxf(m2a, __shfl_xor(m2a, m, 32));
    m2b = fmaxf(m2b, __shfl_xor(m2b, m, 32));
  }

  // ---- p-column weighted sums + m1 pieces (from LDS) ----
  float ps0=0,ps1=0,ps2=0,ps3=0,ps4=0,ps5=0,ps6=0,ps7=0;
  float m1n0=0, m1n1=0, nq1a=0, nq1b=0;
  for (int h = jg; h < HH; h += 32) {
    float pv = pcol[il][h];
    float ql = qlast[h];
    float p2 = pv * pv, q2 = ql * ql, pq = pv * ql;
    ps0 = fmaf(w1sq[0][h], p2, ps0);
    ps1 = fmaf(w1sq[1][h], p2, ps1);
    ps2 = fmaf(w2sq[0][h], p2, ps2);
    ps3 = fmaf(w2sq[1][h], p2, ps3);
    ps4 = fmaf(w3sq[0][h], p2, ps4);
    ps5 = fmaf(w3sq[1][h], p2, ps5);
    ps6 = fmaf(w4sq[0][h], p2, ps6);
    ps7 = fmaf(w4sq[1][h], p2, ps7);
    m1n0 = fmaf(w1sq[0][h], pq, m1n0);
    m1n1 = fmaf(w1sq[1][h], pq, m1n1);
    nq1a = fmaf(w1sq[0][h], q2, nq1a);
    nq1b = fmaf(w1sq[1][h], q2, nq1b);
  }
#pragma unroll
  for (int m = 1; m < 32; m <<= 1) {
    ps0 += __shfl_xor(ps0, m, 32);  ps1 += __shfl_xor(ps1, m, 32);
    ps2 += __shfl_xor(ps2, m, 32);  ps3 += __shfl_xor(ps3, m, 32);
    ps4 += __shfl_xor(ps4, m, 32);  ps5 += __shfl_xor(ps5, m, 32);
    ps6 += __shfl_xor(ps6, m, 32);  ps7 += __shfl_xor(ps7, m, 32);
    m1n0 += __shfl_xor(m1n0, m, 32); m1n1 += __shfl_xor(m1n1, m, 32);
    nq1a += __shfl_xor(nq1a, m, 32); nq1b += __shfl_xor(nq1b, m, 32);
  }

  // ---- Pass 2: hvec per h, m3/m4 accumulation ----
  const float inv_rs = 1.0f / rowsum;
  float m3n0=0,m3n1=0,nh0=0,nh1=0,m4n0=0,m4n1=0,nq4a=0,nq4b=0;
  for (int ht = 0; ht < NT; ++ht) {
    const int h0 = ht * HT;
    __syncthreads();
#pragma unroll
    for (int e = 0; e < (HT * SS) / 256; ++e) {
      int idx = t + e * 256;
      int hh = idx / SS, j = idx % SS;
      qt[hh][j] = qrow0[(size_t)(h0 + hh) * BB * SS + j];
    }
    __syncthreads();
#pragma unroll
    for (int hh = 0; hh < HT; ++hh) {
      const int h = h0 + hh;
      const float4* qr = (const float4*)&qt[hh][jbase];
      float4 q0 = qr[0], q1 = qr[1], q2v = qr[2];
      float partial =
          att[0]*q0.x + att[1]*q0.y + att[2]*q0.z + att[3]*q0.w +
          att[4]*q1.x + att[5]*q1.y + att[6]*q1.z + att[7]*q1.w +
          att[8]*q2v.x + att[9]*q2v.y + att[10]*q2v.z + att[11]*q2v.w;
#pragma unroll
      for (int m = 1; m < 32; m <<= 1) partial += __shfl_xor(partial, m, 32);
      const float hm = partial * inv_rs;         // hmean[h] for this row
      const float pv = pcol[il][h];
      const float qi = qt[hh][aidx];             // hmax[h] (broadcast read)
      const float w30 = w3sq[0][h], w31 = w3sq[1][h];
      const float w40 = w4sq[0][h], w41 = w4sq[1][h];
      m3n0 = fmaf(w30, pv * hm, m3n0);
      m3n1 = fmaf(w31, pv * hm, m3n1);
      nh0  = fmaf(w30, hm * hm, nh0);
      nh1  = fmaf(w31, hm * hm, nh1);
      m4n0 = fmaf(w40, pv * qi, m4n0);
      m4n1 = fmaf(w41, pv * qi, m4n1);
      nq4a = fmaf(w40, qi * qi, nq4a);
      nq4b = fmaf(w41, qi * qi, nq4b);
    }
  }

  // ---- Epilogue: write 8 outputs per row ----
  if (jg == 0) {
    const size_t AS = (size_t)SS * BB * 2;
    const size_t base = (size_t)i * (BB * 2) + (size_t)b * 2;
    float v;
    // m1 -> arrays 0(f)/1(b)
    v = m1n0 / (fmaxf(sqrtf(ps0), EPSF) * fmaxf(sqrtf(nq1a), EPSF));
    out[(size_t)(0 + dir) * AS + base + 0] = v;
    v = m1n1 / (fmaxf(sqrtf(ps1), EPSF) * fmaxf(sqrtf(nq1b), EPSF));
    out[(size_t)(0 + dir) * AS + base + 1] = v;
    // m2 -> arrays 2/3
    out[(size_t)(2 + dir) * AS + base + 0] = m2a / fmaxf(sqrtf(ps2), EPSF);
    out[(size_t)(2 + dir) * AS + base + 1] = m2b / fmaxf(sqrtf(ps3), EPSF);
    // m3 -> arrays 4/5
    v = m3n0 / (fmaxf(sqrtf(ps4), EPSF) * fmaxf(sqrtf(nh0), EPSF));
    out[(size_t)(4 + dir) * AS + base + 0] = v;
    v = m3n1 / (fmaxf(sqrtf(ps5), EPSF) * fmaxf(sqrtf(nh1), EPSF));
    out[(size_t)(4 + dir) * AS + base + 1] = v;
    // m4 -> arrays 6/7
    v = m4n0 / (fmaxf(sqrtf(ps6), EPSF) * fmaxf(sqrtf(nq4a), EPSF));
    out[(size_t)(6 + dir) * AS + base + 0] = v;
    v = m4n1 / (fmaxf(sqrtf(ps7), EPSF) * fmaxf(sqrtf(nq4b), EPSF));
    out[(size_t)(6 + dir) * AS + base + 1] = v;
  }
}

extern "C" void kernel_launch(void* const* d_in, const int* in_sizes, int n_in,
                              void* d_out, int out_size, void* d_ws, size_t ws_size,
                              hipStream_t stream) {
  const float* pf  = (const float*)d_in[0];
  const float* pb  = (const float*)d_in[1];
  const float* qf  = (const float*)d_in[2];
  const float* qb  = (const float*)d_in[3];
  const float* w1f = (const float*)d_in[4];
  const float* w1b = (const float*)d_in[5];
  const float* w2f = (const float*)d_in[6];
  const float* w2b = (const float*)d_in[7];
  const float* w3f = (const float*)d_in[8];
  const float* w4f = (const float*)d_in[10];  // w3b/w4b unused by reference
  float* out = (float*)d_out;
  float* nq2 = (float*)d_ws;  // 6*64*384 floats = 589824 B

  hipLaunchKernelGGL(qnorm_kernel, dim3((2 * BB * SS + 255) / 256), dim3(256), 0, stream,
                     qf, qb, w2f, w2b, nq2);
  hipLaunchKernelGGL(bimpm_kernel, dim3(2 * BB * (SS / IB)), dim3(256), 0, stream,
                     pf, pb, qf, qb, w1f, w1b, w2f, w2b, w3f, w4f, nq2, out);
}

// Round 3
// 406.108 us; speedup vs baseline: 1.8855x; 1.8855x over previous
//
#include <hip/hip_runtime.h>
#include <math.h>

#define HH 100
#define BB 64
#define SS 384
#define IB 8
#define HT 10
#define NT 10
#define JT 32
#define JP 36
#define NJT 12
#define EPSF 1e-6f

// ---------------- Kernel 1: per-(dir,l,b,j) w2-weighted q-norms + plain q-norms ----------------
__global__ __launch_bounds__(256) void qnorm_kernel(
    const float* __restrict__ qf, const float* __restrict__ qb,
    const float* __restrict__ w2f, const float* __restrict__ w2b,
    float* __restrict__ nq2)
{
  int t = blockIdx.x * 256 + threadIdx.x;
  if (t >= 2 * BB * SS) return;
  int dir = t / (BB * SS);
  int rem = t % (BB * SS);
  int b = rem / SS;
  int j = rem % SS;
  const float* q  = dir ? qb  : qf;
  const float* w2 = dir ? w2b : w2f;
  float s0 = 0.f, s1 = 0.f, sp = 0.f;
  for (int h = 0; h < HH; ++h) {
    float qv = q[(size_t)h * BB * SS + (size_t)b * SS + j];
    float w0 = w2[h], w1 = w2[HH + h];
    float q2 = qv * qv;
    s0 = fmaf(w0 * w0, q2, s0);
    s1 = fmaf(w1 * w1, q2, s1);
    sp += q2;
  }
  nq2[((size_t)(dir * 2 + 0) * BB + b) * SS + j] = fmaxf(sqrtf(s0), EPSF);
  nq2[((size_t)(dir * 2 + 1) * BB + b) * SS + j] = fmaxf(sqrtf(s1), EPSF);
  nq2[((size_t)(4 + dir) * BB + b) * SS + j]     = fmaxf(sqrtf(sp), EPSF);
}

// ---------------- Kernel 2: fused main kernel ----------------
__global__ __launch_bounds__(256) void bimpm_kernel(
    const float* __restrict__ pf, const float* __restrict__ pb,
    const float* __restrict__ qf, const float* __restrict__ qb,
    const float* __restrict__ w1f, const float* __restrict__ w1b,
    const float* __restrict__ w2f, const float* __restrict__ w2b,
    const float* __restrict__ w3f_, const float* __restrict__ w4f_,
    const float* __restrict__ nq2ws, float* __restrict__ out)
{
  // qbuf union: pass1 qt[10][384] (3840 f) / pass2 qt2[100][36] (3600 f)
  __shared__ __align__(16) float qbuf[HT * SS];          // 15360 B
  __shared__ __align__(16) float attn_s[IB][SS];         // 12288 B
  __shared__ float hmA[IB][HH];                          // 3200 B
  __shared__ float hmB[IB][HH];                          // 3200 B
  __shared__ float pcol[IB][HH];                         // 3200 B
  __shared__ float2 w2pk[HH];                            // 800 B
  __shared__ float qlast[HH];                            // 400 B
  __shared__ int aidx_s[IB];                             // 32 B

  const int blk = blockIdx.x;
  const int dir = blk / (BB * (SS / IB));
  const int rem = blk % (BB * (SS / IB));
  const int b   = rem / (SS / IB);
  const int i0  = (rem % (SS / IB)) * IB;

  const float* __restrict__ p  = dir ? pb  : pf;
  const float* __restrict__ q  = dir ? qb  : qf;
  const float* __restrict__ w1 = dir ? w1b : w1f;
  const float* __restrict__ w2 = dir ? w2b : w2f;

  const int t  = threadIdx.x;
  const int il = t >> 5;     // row within i-block (0..7)
  const int jg = t & 31;     // lane group over j (0..31)
  const int i  = i0 + il;
  const int jbase = jg * 12;

  // stage packed w2^2
  if (t < HH) {
    float a0 = w2[t], a1 = w2[HH + t];
    w2pk[t] = make_float2(a0 * a0, a1 * a1);
  }
  // stage p columns for this i-block: pcol[ii][h]
  for (int e = t; e < IB * HH; e += 256) {
    int h = e / IB, ii = e % IB;
    pcol[ii][h] = p[(size_t)h * BB * SS + (size_t)b * SS + i0 + ii];
  }
  // stage q's last column
  if (t < HH) qlast[t] = q[(size_t)t * BB * SS + (size_t)b * SS + (SS - 1)];

  const float* __restrict__ qrow0 = q + (size_t)b * SS;

  // ---- Pass 1: raw gram / g2(l=0) / g2(l=1) rows in registers ----
  float att[12], ga[12], gb[12];
#pragma unroll
  for (int k = 0; k < 12; ++k) { att[k] = 0.f; ga[k] = 0.f; gb[k] = 0.f; }

  for (int ht = 0; ht < NT; ++ht) {
    const int h0 = ht * HT;
    __syncthreads();
    // stage 10 rows x 384 floats = 960 quads, float4 loads
#pragma unroll
    for (int k = 0; k < 4; ++k) {
      int e = t + k * 256;
      if (e < (HT * SS) / 4) {
        int hh = e / (SS / 4), qd = e % (SS / 4);
        float4 v = *(const float4*)&qrow0[(size_t)(h0 + hh) * BB * SS + qd * 4];
        *(float4*)&qbuf[hh * SS + qd * 4] = v;
      }
    }
    __syncthreads();
#pragma unroll
    for (int hh = 0; hh < HT; ++hh) {
      const int h = h0 + hh;
      const float pv  = pcol[il][h];
      const float2 w2v = w2pk[h];
      const float pa  = pv * w2v.x;
      const float pbv = pv * w2v.y;
      const float4* qr = (const float4*)&qbuf[hh * SS + jbase];
#pragma unroll
      for (int kk = 0; kk < 3; ++kk) {
        float4 qv = qr[kk];
        att[kk*4+0] = fmaf(pv,  qv.x, att[kk*4+0]);
        att[kk*4+1] = fmaf(pv,  qv.y, att[kk*4+1]);
        att[kk*4+2] = fmaf(pv,  qv.z, att[kk*4+2]);
        att[kk*4+3] = fmaf(pv,  qv.w, att[kk*4+3]);
        ga[kk*4+0]  = fmaf(pa,  qv.x, ga[kk*4+0]);
        ga[kk*4+1]  = fmaf(pa,  qv.y, ga[kk*4+1]);
        ga[kk*4+2]  = fmaf(pa,  qv.z, ga[kk*4+2]);
        ga[kk*4+3]  = fmaf(pa,  qv.w, ga[kk*4+3]);
        gb[kk*4+0]  = fmaf(pbv, qv.x, gb[kk*4+0]);
        gb[kk*4+1]  = fmaf(pbv, qv.y, gb[kk*4+1]);
        gb[kk*4+2]  = fmaf(pbv, qv.z, gb[kk*4+2]);
        gb[kk*4+3]  = fmaf(pbv, qv.w, gb[kk*4+3]);
      }
    }
  }

  // ---- Pass 1b: rescale by |q_j|, row reductions (one butterfly set) ----
  float rowsum = 0.f;
  float amax = -INFINITY; int aidx = 0;
  float m2a = -INFINITY, m2b = -INFINITY;
  {
    const float* nqa = nq2ws + ((size_t)(dir * 2 + 0) * BB + b) * SS + jbase;
    const float* nqb = nq2ws + ((size_t)(dir * 2 + 1) * BB + b) * SS + jbase;
    const float* nqp = nq2ws + ((size_t)(4 + dir) * BB + b) * SS + jbase;
#pragma unroll
    for (int k = 0; k < 12; ++k) {
      float d = att[k] / nqp[k];   // cosine * |p_i| ; |p_i| cancels in attn & argmax
      att[k] = d;
      rowsum += d;
      if (d > amax) { amax = d; aidx = jbase + k; }
      m2a = fmaxf(m2a, ga[k] / nqa[k]);
      m2b = fmaxf(m2b, gb[k] / nqb[k]);
    }
  }
#pragma unroll
  for (int m = 1; m < 32; m <<= 1) {
    rowsum += __shfl_xor(rowsum, m, 32);
    float ov = __shfl_xor(amax, m, 32);
    int   oi = __shfl_xor(aidx, m, 32);
    if (ov > amax || (ov == amax && oi < aidx)) { amax = ov; aidx = oi; }
    m2a = fmaxf(m2a, __shfl_xor(m2a, m, 32));
    m2b = fmaxf(m2b, __shfl_xor(m2b, m, 32));
  }
  // write normalized attn row to LDS (attn = d / rowsum)
  {
    const float inv_rs = 1.0f / rowsum;
    float4 v0 = make_float4(att[0]*inv_rs, att[1]*inv_rs, att[2]*inv_rs, att[3]*inv_rs);
    float4 v1 = make_float4(att[4]*inv_rs, att[5]*inv_rs, att[6]*inv_rs, att[7]*inv_rs);
    float4 v2 = make_float4(att[8]*inv_rs, att[9]*inv_rs, att[10]*inv_rs, att[11]*inv_rs);
    *(float4*)&attn_s[il][jbase + 0] = v0;
    *(float4*)&attn_s[il][jbase + 4] = v1;
    *(float4*)&attn_s[il][jbase + 8] = v2;
    if (jg == 0) aidx_s[il] = aidx;
  }

  // ---- Pass 2: hv[row] per owned h, no shuffles ----
  const int grp  = t >> 7;      // 0: waves 0-1 (j-half 0), 1: waves 2-3 (j-half 1)
  const int hown = t & 127;     // owned h if < 100
  float hv[IB];
#pragma unroll
  for (int r = 0; r < IB; ++r) hv[r] = 0.f;

  for (int jt = 0; jt < NJT; ++jt) {
    const int j0 = jt * JT;
    __syncthreads();   // prev compute / pass-1 reads / attn writes done
    // stage qt2[100][36]: 100 rows x 8 quads = 800 quads
#pragma unroll
    for (int k = 0; k < 4; ++k) {
      int e = t + k * 256;
      if (e < HH * (JT / 4)) {
        int hh = e / (JT / 4), qd = e % (JT / 4);
        float4 v = *(const float4*)&qrow0[(size_t)hh * BB * SS + j0 + qd * 4];
        *(float4*)&qbuf[hh * JP + qd * 4] = v;
      }
    }
    __syncthreads();
    if (hown < HH) {
      const float* qrowL = &qbuf[hown * JP];
#pragma unroll
      for (int qd2 = 0; qd2 < 4; ++qd2) {
        const int qd = grp * 4 + qd2;
        float4 qv = *(const float4*)&qrowL[qd * 4];
#pragma unroll
        for (int r = 0; r < IB; ++r) {
          float4 av = *(const float4*)&attn_s[r][j0 + qd * 4];
          hv[r] = fmaf(av.x, qv.x, fmaf(av.y, qv.y, fmaf(av.z, qv.z, fmaf(av.w, qv.w, hv[r]))));
        }
      }
    }
  }
  if (hown < HH) {
    float* hmdst = grp ? &hmB[0][0] : &hmA[0][0];
#pragma unroll
    for (int r = 0; r < IB; ++r) hmdst[r * HH + hown] = hv[r];
  }
  __syncthreads();

  // ---- Final m3/m4 phase: thread = (il, lane-strided h), one butterfly set ----
  float m3n0=0,m3n1=0,nh0=0,nh1=0,m4n0=0,m4n1=0,nq4a=0,nq4b=0;
  {
    const int ax = aidx_s[il];
#pragma unroll
    for (int k = 0; k < 4; ++k) {
      const int h = jg + 32 * k;
      if (h < HH) {
        float hm = hmA[il][h] + hmB[il][h];
        float pv = pcol[il][h];
        float qi = qrow0[(size_t)h * BB * SS + ax];  // global, L2-hot
        float w3a = w3f_[h], w3b = w3f_[HH + h];
        float w4a = w4f_[h], w4b = w4f_[HH + h];
        float w30 = w3a * w3a, w31 = w3b * w3b;
        float w40 = w4a * w4a, w41 = w4b * w4b;
        m3n0 = fmaf(w30, pv * hm, m3n0);
        m3n1 = fmaf(w31, pv * hm, m3n1);
        nh0  = fmaf(w30, hm * hm, nh0);
        nh1  = fmaf(w31, hm * hm, nh1);
        m4n0 = fmaf(w40, pv * qi, m4n0);
        m4n1 = fmaf(w41, pv * qi, m4n1);
        nq4a = fmaf(w40, qi * qi, nq4a);
        nq4b = fmaf(w41, qi * qi, nq4b);
      }
    }
  }
#pragma unroll
  for (int m = 1; m < 32; m <<= 1) {
    m3n0 += __shfl_xor(m3n0, m, 32); m3n1 += __shfl_xor(m3n1, m, 32);
    nh0  += __shfl_xor(nh0,  m, 32); nh1  += __shfl_xor(nh1,  m, 32);
    m4n0 += __shfl_xor(m4n0, m, 32); m4n1 += __shfl_xor(m4n1, m, 32);
    nq4a += __shfl_xor(nq4a, m, 32); nq4b += __shfl_xor(nq4b, m, 32);
  }

  // ---- p-column weighted sums + m1 pieces ----
  float ps0=0,ps1=0,ps2=0,ps3=0,ps4=0,ps5=0,ps6=0,ps7=0;
  float m1n0=0, m1n1=0, nq1a=0, nq1b=0;
  for (int h = jg; h < HH; h += 32) {
    float pv = pcol[il][h];
    float ql = qlast[h];
    float p2 = pv * pv, q2 = ql * ql, pq = pv * ql;
    float w1a = w1[h], w1bv = w1[HH + h];
    float w3a = w3f_[h], w3b = w3f_[HH + h];
    float w4a = w4f_[h], w4b = w4f_[HH + h];
    float2 w2v = w2pk[h];
    float w10 = w1a * w1a, w11 = w1bv * w1bv;
    ps0 = fmaf(w10, p2, ps0);
    ps1 = fmaf(w11, p2, ps1);
    ps2 = fmaf(w2v.x, p2, ps2);
    ps3 = fmaf(w2v.y, p2, ps3);
    ps4 = fmaf(w3a * w3a, p2, ps4);
    ps5 = fmaf(w3b * w3b, p2, ps5);
    ps6 = fmaf(w4a * w4a, p2, ps6);
    ps7 = fmaf(w4b * w4b, p2, ps7);
    m1n0 = fmaf(w10, pq, m1n0);
    m1n1 = fmaf(w11, pq, m1n1);
    nq1a = fmaf(w10, q2, nq1a);
    nq1b = fmaf(w11, q2, nq1b);
  }
#pragma unroll
  for (int m = 1; m < 32; m <<= 1) {
    ps0 += __shfl_xor(ps0, m, 32);  ps1 += __shfl_xor(ps1, m, 32);
    ps2 += __shfl_xor(ps2, m, 32);  ps3 += __shfl_xor(ps3, m, 32);
    ps4 += __shfl_xor(ps4, m, 32);  ps5 += __shfl_xor(ps5, m, 32);
    ps6 += __shfl_xor(ps6, m, 32);  ps7 += __shfl_xor(ps7, m, 32);
    m1n0 += __shfl_xor(m1n0, m, 32); m1n1 += __shfl_xor(m1n1, m, 32);
    nq1a += __shfl_xor(nq1a, m, 32); nq1b += __shfl_xor(nq1b, m, 32);
  }

  // ---- Epilogue: write 8 outputs per row ----
  if (jg == 0) {
    const size_t AS = (size_t)SS * BB * 2;
    const size_t base = (size_t)i * (BB * 2) + (size_t)b * 2;
    float v;
    v = m1n0 / (fmaxf(sqrtf(ps0), EPSF) * fmaxf(sqrtf(nq1a), EPSF));
    out[(size_t)(0 + dir) * AS + base + 0] = v;
    v = m1n1 / (fmaxf(sqrtf(ps1), EPSF) * fmaxf(sqrtf(nq1b), EPSF));
    out[(size_t)(0 + dir) * AS + base + 1] = v;
    out[(size_t)(2 + dir) * AS + base + 0] = m2a / fmaxf(sqrtf(ps2), EPSF);
    out[(size_t)(2 + dir) * AS + base + 1] = m2b / fmaxf(sqrtf(ps3), EPSF);
    v = m3n0 / (fmaxf(sqrtf(ps4), EPSF) * fmaxf(sqrtf(nh0), EPSF));
    out[(size_t)(4 + dir) * AS + base + 0] = v;
    v = m3n1 / (fmaxf(sqrtf(ps5), EPSF) * fmaxf(sqrtf(nh1), EPSF));
    out[(size_t)(4 + dir) * AS + base + 1] = v;
    v = m4n0 / (fmaxf(sqrtf(ps6), EPSF) * fmaxf(sqrtf(nq4a), EPSF));
    out[(size_t)(6 + dir) * AS + base + 0] = v;
    v = m4n1 / (fmaxf(sqrtf(ps7), EPSF) * fmaxf(sqrtf(nq4b), EPSF));
    out[(size_t)(6 + dir) * AS + base + 1] = v;
  }
}

extern "C" void kernel_launch(void* const* d_in, const int* in_sizes, int n_in,
                              void* d_out, int out_size, void* d_ws, size_t ws_size,
                              hipStream_t stream) {
  const float* pf  = (const float*)d_in[0];
  const float* pb  = (const float*)d_in[1];
  const float* qf  = (const float*)d_in[2];
  const float* qb  = (const float*)d_in[3];
  const float* w1f = (const float*)d_in[4];
  const float* w1b = (const float*)d_in[5];
  const float* w2f = (const float*)d_in[6];
  const float* w2b = (const float*)d_in[7];
  const float* w3f = (const float*)d_in[8];
  const float* w4f = (const float*)d_in[10];  // w3b/w4b unused by reference
  float* out = (float*)d_out;
  float* nq2 = (float*)d_ws;  // 6*64*384 floats = 589824 B

  hipLaunchKernelGGL(qnorm_kernel, dim3((2 * BB * SS + 255) / 256), dim3(256), 0, stream,
                     qf, qb, w2f, w2b, nq2);
  hipLaunchKernelGGL(bimpm_kernel, dim3(2 * BB * (SS / IB)), dim3(256), 0, stream,
                     pf, pb, qf, qb, w1f, w1b, w2f, w2b, w3f, w4f, nq2, out);
}

// Round 4
// 378.261 us; speedup vs baseline: 2.0243x; 1.0736x over previous
//
#include <hip/hip_runtime.h>
#include <math.h>

#define HH 100
#define BB 64
#define SS 384
#define IB 16
#define HT 10
#define NT 10
#define JT 32
#define JP 36
#define NJT 12
#define PCP 18
#define EPSF 1e-6f

// ---------------- Kernel 1: reciprocal norms: 1/max(sqrt(.),eps) ----------------
__global__ __launch_bounds__(256) void qnorm_kernel(
    const float* __restrict__ qf, const float* __restrict__ qb,
    const float* __restrict__ w2f, const float* __restrict__ w2b,
    float* __restrict__ nq2)
{
  int t = blockIdx.x * 256 + threadIdx.x;
  if (t >= 2 * BB * SS) return;
  int dir = t / (BB * SS);
  int rem = t % (BB * SS);
  int b = rem / SS;
  int j = rem % SS;
  const float* q  = dir ? qb  : qf;
  const float* w2 = dir ? w2b : w2f;
  float s0 = 0.f, s1 = 0.f, sp = 0.f;
  for (int h = 0; h < HH; ++h) {
    float qv = q[(size_t)h * BB * SS + (size_t)b * SS + j];
    float w0 = w2[h], w1 = w2[HH + h];
    float q2 = qv * qv;
    s0 = fmaf(w0 * w0, q2, s0);
    s1 = fmaf(w1 * w1, q2, s1);
    sp += q2;
  }
  nq2[((size_t)(dir * 2 + 0) * BB + b) * SS + j] = 1.0f / fmaxf(sqrtf(s0), EPSF);
  nq2[((size_t)(dir * 2 + 1) * BB + b) * SS + j] = 1.0f / fmaxf(sqrtf(s1), EPSF);
  nq2[((size_t)(4 + dir) * BB + b) * SS + j]     = 1.0f / fmaxf(sqrtf(sp), EPSF);
}

// ---------------- Kernel 2: fused main kernel ----------------
__global__ __launch_bounds__(256) void bimpm_kernel(
    const float* __restrict__ pf, const float* __restrict__ pb,
    const float* __restrict__ qf, const float* __restrict__ qb,
    const float* __restrict__ w1f, const float* __restrict__ w1b,
    const float* __restrict__ w2f, const float* __restrict__ w2b,
    const float* __restrict__ w3f_, const float* __restrict__ w4f_,
    const float* __restrict__ nq2ws, float* __restrict__ out)
{
  // qbuf: pass1 q tiles [10][384]; pass2 q tiles [100][36] (3600); then hm[2][16][100] (3200)
  __shared__ __align__(16) float qbuf[HT * SS];          // 15360 B
  __shared__ __align__(16) float attn_s[IB][SS];         // 24576 B
  __shared__ __align__(16) float pcolT[HH * PCP];        // 7200 B
  __shared__ float2 w2pk[HH];                            // 800 B
  __shared__ float qlast[HH];                            // 400 B
  __shared__ float ps_s[IB][6];                          // 384 B  (rps2a,rps2b,rps3a,rps3b,rps4a,rps4b)
  __shared__ int aidx_s[IB];                             // 64 B

  const int blk = blockIdx.x;
  const int nib = SS / IB;                   // 24
  const int dir = blk / (BB * nib);
  const int rem = blk % (BB * nib);
  const int b   = rem / nib;
  const int i0  = (rem % nib) * IB;

  const float* __restrict__ p  = dir ? pb  : pf;
  const float* __restrict__ q  = dir ? qb  : qf;
  const float* __restrict__ w1 = dir ? w1b : w1f;
  const float* __restrict__ w2 = dir ? w2b : w2f;

  const int t  = threadIdx.x;
  const int w  = t >> 6;        // wave 0..3
  const int l  = t & 63;
  const int hs = l >> 5;        // lane half
  const int jg = l & 31;
  const int jbase = jg * 12;
  const int lr0 = w * 4 + hs * 2;   // first of this lane's 2 rows

  const size_t AS = (size_t)SS * BB * 2;

  // ---- stage weights, pcolT, qlast ----
  if (t < HH) {
    float a0 = w2[t], a1 = w2[HH + t];
    w2pk[t] = make_float2(a0 * a0, a1 * a1);
    qlast[t] = q[(size_t)t * BB * SS + (size_t)b * SS + (SS - 1)];
  }
  for (int e = t; e < HH * IB; e += 256) {
    int h = e >> 4, ii = e & 15;
    pcolT[h * PCP + ii] = p[(size_t)h * BB * SS + (size_t)b * SS + i0 + ii];
  }
  __syncthreads();

  const float* __restrict__ qrow0 = q + (size_t)b * SS;

  // ---- psm1 phase: per-row weighted p-norm recips + m1 outputs ----
  {
    const int row = t >> 4, hl = t & 15;
    float ps0=0,ps1=0,ps2=0,ps3=0,ps4=0,ps5=0,ps6=0,ps7=0;
    float m1n0=0,m1n1=0,nq1a=0,nq1b=0;
    for (int h = hl; h < HH; h += 16) {
      float pv = pcolT[h * PCP + row];
      float ql = qlast[h];
      float p2 = pv * pv, q2 = ql * ql, pq = pv * ql;
      float w1a = w1[h], w1bv = w1[HH + h];
      float w3a = w3f_[h], w3b = w3f_[HH + h];
      float w4a = w4f_[h], w4b = w4f_[HH + h];
      float2 w2v = w2pk[h];
      float w10 = w1a * w1a, w11 = w1bv * w1bv;
      ps0 = fmaf(w10, p2, ps0);       ps1 = fmaf(w11, p2, ps1);
      ps2 = fmaf(w2v.x, p2, ps2);     ps3 = fmaf(w2v.y, p2, ps3);
      ps4 = fmaf(w3a * w3a, p2, ps4); ps5 = fmaf(w3b * w3b, p2, ps5);
      ps6 = fmaf(w4a * w4a, p2, ps6); ps7 = fmaf(w4b * w4b, p2, ps7);
      m1n0 = fmaf(w10, pq, m1n0);     m1n1 = fmaf(w11, pq, m1n1);
      nq1a = fmaf(w10, q2, nq1a);     nq1b = fmaf(w11, q2, nq1b);
    }
#pragma unroll
    for (int m = 1; m < 16; m <<= 1) {
      ps0 += __shfl_xor(ps0, m, 16);  ps1 += __shfl_xor(ps1, m, 16);
      ps2 += __shfl_xor(ps2, m, 16);  ps3 += __shfl_xor(ps3, m, 16);
      ps4 += __shfl_xor(ps4, m, 16);  ps5 += __shfl_xor(ps5, m, 16);
      ps6 += __shfl_xor(ps6, m, 16);  ps7 += __shfl_xor(ps7, m, 16);
      m1n0 += __shfl_xor(m1n0, m, 16); m1n1 += __shfl_xor(m1n1, m, 16);
      nq1a += __shfl_xor(nq1a, m, 16); nq1b += __shfl_xor(nq1b, m, 16);
    }
    if (hl == 0) {
      const size_t base = (size_t)(i0 + row) * (BB * 2) + (size_t)b * 2;
      out[(size_t)(0 + dir) * AS + base + 0] =
          m1n0 / (fmaxf(sqrtf(ps0), EPSF) * fmaxf(sqrtf(nq1a), EPSF));
      out[(size_t)(0 + dir) * AS + base + 1] =
          m1n1 / (fmaxf(sqrtf(ps1), EPSF) * fmaxf(sqrtf(nq1b), EPSF));
      ps_s[row][0] = 1.0f / fmaxf(sqrtf(ps2), EPSF);
      ps_s[row][1] = 1.0f / fmaxf(sqrtf(ps3), EPSF);
      ps_s[row][2] = 1.0f / fmaxf(sqrtf(ps4), EPSF);
      ps_s[row][3] = 1.0f / fmaxf(sqrtf(ps5), EPSF);
      ps_s[row][4] = 1.0f / fmaxf(sqrtf(ps6), EPSF);
      ps_s[row][5] = 1.0f / fmaxf(sqrtf(ps7), EPSF);
    }
  }

  // ---- Pass 1: grams, 2 rows per lane ----
  float att[2][12], ga[2][12], gb[2][12];
#pragma unroll
  for (int r = 0; r < 2; ++r)
#pragma unroll
    for (int k = 0; k < 12; ++k) { att[r][k] = 0.f; ga[r][k] = 0.f; gb[r][k] = 0.f; }

  for (int ht = 0; ht < NT; ++ht) {
    const int h0 = ht * HT;
    __syncthreads();
#pragma unroll
    for (int k = 0; k < 4; ++k) {
      int e = t + k * 256;
      if (e < (HT * SS) / 4) {
        int hh = e / (SS / 4), qd = e % (SS / 4);
        float4 v = *(const float4*)&qrow0[(size_t)(h0 + hh) * BB * SS + qd * 4];
        *(float4*)&qbuf[hh * SS + qd * 4] = v;
      }
    }
    __syncthreads();
#pragma unroll
    for (int hh = 0; hh < HT; ++hh) {
      const int h = h0 + hh;
      const float2 pT = *(const float2*)&pcolT[h * PCP + lr0];
      const float2 w2v = w2pk[h];
      const float pa0 = pT.x * w2v.x, pb0 = pT.x * w2v.y;
      const float pa1 = pT.y * w2v.x, pb1 = pT.y * w2v.y;
      const float4* qr = (const float4*)&qbuf[hh * SS + jbase];
#pragma unroll
      for (int kk = 0; kk < 3; ++kk) {
        float4 qv = qr[kk];
        float qe[4] = {qv.x, qv.y, qv.z, qv.w};
#pragma unroll
        for (int c = 0; c < 4; ++c) {
          int k = kk * 4 + c;
          att[0][k] = fmaf(pT.x, qe[c], att[0][k]);
          att[1][k] = fmaf(pT.y, qe[c], att[1][k]);
          ga[0][k]  = fmaf(pa0,  qe[c], ga[0][k]);
          ga[1][k]  = fmaf(pa1,  qe[c], ga[1][k]);
          gb[0][k]  = fmaf(pb0,  qe[c], gb[0][k]);
          gb[1][k]  = fmaf(pb1,  qe[c], gb[1][k]);
        }
      }
    }
  }

  // ---- Pass 1b: rescale (multiply by recip), reduce, write attn + m2 ----
  {
    const float* nqa = nq2ws + ((size_t)(dir * 2 + 0) * BB + b) * SS + jbase;
    const float* nqb = nq2ws + ((size_t)(dir * 2 + 1) * BB + b) * SS + jbase;
    const float* nqp = nq2ws + ((size_t)(4 + dir) * BB + b) * SS + jbase;
    float ra[12], rb[12], rp[12];
#pragma unroll
    for (int kk = 0; kk < 3; ++kk) {
      float4 va = ((const float4*)nqa)[kk];
      float4 vb = ((const float4*)nqb)[kk];
      float4 vp = ((const float4*)nqp)[kk];
      ra[kk*4+0]=va.x; ra[kk*4+1]=va.y; ra[kk*4+2]=va.z; ra[kk*4+3]=va.w;
      rb[kk*4+0]=vb.x; rb[kk*4+1]=vb.y; rb[kk*4+2]=vb.z; rb[kk*4+3]=vb.w;
      rp[kk*4+0]=vp.x; rp[kk*4+1]=vp.y; rp[kk*4+2]=vp.z; rp[kk*4+3]=vp.w;
    }
#pragma unroll
    for (int r = 0; r < 2; ++r) {
      float rowsum = 0.f;
      float amax = -INFINITY; int aidx = 0;
      float m2a = -INFINITY, m2b = -INFINITY;
#pragma unroll
      for (int k = 0; k < 12; ++k) {
        float d = att[r][k] * rp[k];
        att[r][k] = d;
        rowsum += d;
        if (d > amax) { amax = d; aidx = jbase + k; }
        m2a = fmaxf(m2a, ga[r][k] * ra[k]);
        m2b = fmaxf(m2b, gb[r][k] * rb[k]);
      }
#pragma unroll
      for (int m = 1; m < 32; m <<= 1) {
        rowsum += __shfl_xor(rowsum, m, 32);
        float ov = __shfl_xor(amax, m, 32);
        int   oi = __shfl_xor(aidx, m, 32);
        if (ov > amax || (ov == amax && oi < aidx)) { amax = ov; aidx = oi; }
        m2a = fmaxf(m2a, __shfl_xor(m2a, m, 32));
        m2b = fmaxf(m2b, __shfl_xor(m2b, m, 32));
      }
      const int lr = lr0 + r;
      const float inv_rs = 1.0f / rowsum;
      *(float4*)&attn_s[lr][jbase + 0] =
          make_float4(att[r][0]*inv_rs, att[r][1]*inv_rs, att[r][2]*inv_rs, att[r][3]*inv_rs);
      *(float4*)&attn_s[lr][jbase + 4] =
          make_float4(att[r][4]*inv_rs, att[r][5]*inv_rs, att[r][6]*inv_rs, att[r][7]*inv_rs);
      *(float4*)&attn_s[lr][jbase + 8] =
          make_float4(att[r][8]*inv_rs, att[r][9]*inv_rs, att[r][10]*inv_rs, att[r][11]*inv_rs);
      if (jg == 0) {
        aidx_s[lr] = aidx;
        const size_t base = (size_t)(i0 + lr) * (BB * 2) + (size_t)b * 2;
        out[(size_t)(2 + dir) * AS + base + 0] = m2a * ps_s[lr][0];
        out[(size_t)(2 + dir) * AS + base + 1] = m2b * ps_s[lr][1];
      }
    }
  }

  // ---- Pass 2: hv[16] per owned h ----
  const int grp  = t >> 7;
  const int hown = t & 127;
  float hv[IB];
#pragma unroll
  for (int r = 0; r < IB; ++r) hv[r] = 0.f;

  for (int jt = 0; jt < NJT; ++jt) {
    const int j0 = jt * JT;
    __syncthreads();
#pragma unroll
    for (int k = 0; k < 4; ++k) {
      int e = t + k * 256;
      if (e < HH * (JT / 4)) {
        int hh = e >> 3, qd = e & 7;
        float4 v = *(const float4*)&qrow0[(size_t)hh * BB * SS + j0 + qd * 4];
        *(float4*)&qbuf[hh * JP + qd * 4] = v;
      }
    }
    __syncthreads();
    if (hown < HH) {
      const float* qrowL = &qbuf[hown * JP];
#pragma unroll
      for (int qd2 = 0; qd2 < 4; ++qd2) {
        const int qd = grp * 4 + qd2;
        float4 qv = *(const float4*)&qrowL[qd * 4];
#pragma unroll
        for (int r = 0; r < IB; ++r) {
          float4 av = *(const float4*)&attn_s[r][j0 + qd * 4];
          hv[r] = fmaf(av.x, qv.x, fmaf(av.y, qv.y, fmaf(av.z, qv.z, fmaf(av.w, qv.w, hv[r]))));
        }
      }
    }
  }
  __syncthreads();   // all pass-2 q reads done; qbuf now reused for hm
  if (hown < HH) {
#pragma unroll
    for (int r = 0; r < IB; ++r) qbuf[grp * (IB * HH) + r * HH + hown] = hv[r];
  }
  __syncthreads();

  // ---- Final m3/m4 phase ----
  {
    const int row = t >> 4, hl = t & 15;
    const int ax = aidx_s[row];
    float m3n0=0,m3n1=0,nh0=0,nh1=0,m4n0=0,m4n1=0,nq4a=0,nq4b=0;
    for (int h = hl; h < HH; h += 16) {
      float hm = qbuf[row * HH + h] + qbuf[IB * HH + row * HH + h];
      float pv = pcolT[h * PCP + row];
      float qi = qrow0[(size_t)h * BB * SS + ax];
      float w3a = w3f_[h], w3b = w3f_[HH + h];
      float w4a = w4f_[h], w4b = w4f_[HH + h];
      float w30 = w3a * w3a, w31 = w3b * w3b;
      float w40 = w4a * w4a, w41 = w4b * w4b;
      m3n0 = fmaf(w30, pv * hm, m3n0);
      m3n1 = fmaf(w31, pv * hm, m3n1);
      nh0  = fmaf(w30, hm * hm, nh0);
      nh1  = fmaf(w31, hm * hm, nh1);
      m4n0 = fmaf(w40, pv * qi, m4n0);
      m4n1 = fmaf(w41, pv * qi, m4n1);
      nq4a = fmaf(w40, qi * qi, nq4a);
      nq4b = fmaf(w41, qi * qi, nq4b);
    }
#pragma unroll
    for (int m = 1; m < 16; m <<= 1) {
      m3n0 += __shfl_xor(m3n0, m, 16); m3n1 += __shfl_xor(m3n1, m, 16);
      nh0  += __shfl_xor(nh0,  m, 16); nh1  += __shfl_xor(nh1,  m, 16);
      m4n0 += __shfl_xor(m4n0, m, 16); m4n1 += __shfl_xor(m4n1, m, 16);
      nq4a += __shfl_xor(nq4a, m, 16); nq4b += __shfl_xor(nq4b, m, 16);
    }
    if (hl == 0) {
      const size_t base = (size_t)(i0 + row) * (BB * 2) + (size_t)b * 2;
      out[(size_t)(4 + dir) * AS + base + 0] =
          m3n0 * ps_s[row][2] / fmaxf(sqrtf(nh0), EPSF);
      out[(size_t)(4 + dir) * AS + base + 1] =
          m3n1 * ps_s[row][3] / fmaxf(sqrtf(nh1), EPSF);
      out[(size_t)(6 + dir) * AS + base + 0] =
          m4n0 * ps_s[row][4] / fmaxf(sqrtf(nq4a), EPSF);
      out[(size_t)(6 + dir) * AS + base + 1] =
          m4n1 * ps_s[row][5] / fmaxf(sqrtf(nq4b), EPSF);
    }
  }
}

extern "C" void kernel_launch(void* const* d_in, const int* in_sizes, int n_in,
                              void* d_out, int out_size, void* d_ws, size_t ws_size,
                              hipStream_t stream) {
  const float* pf  = (const float*)d_in[0];
  const float* pb  = (const float*)d_in[1];
  const float* qf  = (const float*)d_in[2];
  const float* qb  = (const float*)d_in[3];
  const float* w1f = (const float*)d_in[4];
  const float* w1b = (const float*)d_in[5];
  const float* w2f = (const float*)d_in[6];
  const float* w2b = (const float*)d_in[7];
  const float* w3f = (const float*)d_in[8];
  const float* w4f = (const float*)d_in[10];  // w3b/w4b unused by reference
  float* out = (float*)d_out;
  float* nq2 = (float*)d_ws;  // 6*64*384 floats

  hipLaunchKernelGGL(qnorm_kernel, dim3((2 * BB * SS + 255) / 256), dim3(256), 0, stream,
                     qf, qb, w2f, w2b, nq2);
  hipLaunchKernelGGL(bimpm_kernel, dim3(2 * BB * (SS / IB)), dim3(256), 0, stream,
                     pf, pb, qf, qb, w1f, w1b, w2f, w2b, w3f, w4f, nq2, out);
}

// Round 5
// 327.513 us; speedup vs baseline: 2.3379x; 1.1549x over previous
//
#include <hip/hip_runtime.h>
#include <math.h>

#define HH 100
#define HP 112          // padded H for pass-2 N tiles (7x16)
#define KP 136          // padded K pitch (bf16 elems) for pass-1 (4x32 + bank pad)
#define BB 64
#define SS 384
#define IB 16
#define DP 392          // d_lds pitch (bf16 elems)
#define EPSF 1e-6f

typedef __attribute__((ext_vector_type(8))) short bf16x8;
typedef __attribute__((ext_vector_type(4))) float f32x4;

__device__ __forceinline__ ushort f2bf(float x) {
  unsigned u = __float_as_uint(x);
  unsigned r = (u + 0x7FFFu + ((u >> 16) & 1u)) >> 16;
  return (ushort)r;
}
__device__ __forceinline__ float bf2f(ushort h) {
  return __uint_as_float(((unsigned)h) << 16);
}

// ---------------- Kernel 1a: reciprocal norms ----------------
__global__ __launch_bounds__(256) void qnorm_kernel(
    const float* __restrict__ qf, const float* __restrict__ qb,
    const float* __restrict__ w2f, const float* __restrict__ w2b,
    float* __restrict__ nq2)
{
  int t = blockIdx.x * 256 + threadIdx.x;
  if (t >= 2 * BB * SS) return;
  int dir = t / (BB * SS);
  int rem = t % (BB * SS);
  int b = rem / SS;
  int j = rem % SS;
  const float* q  = dir ? qb  : qf;
  const float* w2 = dir ? w2b : w2f;
  float s0 = 0.f, s1 = 0.f, sp = 0.f;
  for (int h = 0; h < HH; ++h) {
    float qv = q[(size_t)h * BB * SS + (size_t)b * SS + j];
    float w0 = w2[h], w1 = w2[HH + h];
    float q2 = qv * qv;
    s0 = fmaf(w0 * w0, q2, s0);
    s1 = fmaf(w1 * w1, q2, s1);
    sp += q2;
  }
  nq2[((size_t)(dir * 2 + 0) * BB + b) * SS + j] = 1.0f / fmaxf(sqrtf(s0), EPSF);
  nq2[((size_t)(dir * 2 + 1) * BB + b) * SS + j] = 1.0f / fmaxf(sqrtf(s1), EPSF);
  nq2[((size_t)(4 + dir) * BB + b) * SS + j]     = 1.0f / fmaxf(sqrtf(sp), EPSF);
}

// ---------------- Kernel 1b: elementwise bf16 hi/lo split of q, [dir][hp][b][j] ----------------
__global__ __launch_bounds__(256) void qsplit_kernel(
    const float* __restrict__ qf, const float* __restrict__ qb,
    ushort* __restrict__ qhj_hi, ushort* __restrict__ qhj_lo)
{
  size_t idx = (size_t)blockIdx.x * 256 + threadIdx.x;   // < 2*112*64*384
  int j = (int)(idx % SS);
  size_t r = idx / SS;
  int b = (int)(r % BB); r /= BB;
  int hp = (int)(r % HP);
  int dir = (int)(r / HP);
  float x = 0.f;
  if (hp < HH) x = (dir ? qb : qf)[((size_t)hp * BB + b) * SS + j];
  ushort hi = f2bf(x);
  qhj_hi[idx] = hi;
  qhj_lo[idx] = f2bf(x - bf2f(hi));
}

// ---------------- Kernel 1c: transposed bf16 split, qT[dir][b][j][KP] ----------------
__global__ __launch_bounds__(256) void qtbuild_kernel(
    const float* __restrict__ qf, const float* __restrict__ qb,
    ushort* __restrict__ qT_hi, ushort* __restrict__ qT_lo)
{
  __shared__ __align__(16) float tile[HH * 68];   // [h][j-pad 68]
  const int dir = blockIdx.x >> 6;
  const int b   = blockIdx.x & 63;
  const float* q = dir ? qb : qf;
  const int t = threadIdx.x;
  for (int jt = 0; jt < 6; ++jt) {
    const int j0 = jt * 64;
    __syncthreads();
    for (int e = t; e < HH * 16; e += 256) {
      int h = e >> 4, j4 = e & 15;
      float4 v = *(const float4*)&q[((size_t)h * BB + b) * SS + j0 + j4 * 4];
      *(float4*)&tile[h * 68 + j4 * 4] = v;
    }
    __syncthreads();
    for (int e = t; e < 64 * KP; e += 256) {
      int jj = e / KP, hp = e % KP;
      float x = (hp < HH) ? tile[hp * 68 + jj] : 0.f;
      ushort hi = f2bf(x);
      size_t o = ((size_t)(dir * BB + b) * SS + j0 + jj) * KP + hp;
      qT_hi[o] = hi;
      qT_lo[o] = f2bf(x - bf2f(hi));
    }
  }
}

// ---------------- Kernel 2: MFMA main kernel ----------------
__global__ __launch_bounds__(256) void bimpm_mfma(
    const float* __restrict__ pf, const float* __restrict__ pb,
    const float* __restrict__ qf, const float* __restrict__ qb,
    const float* __restrict__ w1f, const float* __restrict__ w1b,
    const float* __restrict__ w2f, const float* __restrict__ w2b,
    const float* __restrict__ w3f_, const float* __restrict__ w4f_,
    const float* __restrict__ nq2ws,
    const ushort* __restrict__ qhj_hi, const ushort* __restrict__ qhj_lo,
    const ushort* __restrict__ qTg_hi, const ushort* __restrict__ qTg_lo,
    float* __restrict__ out)
{
  // LDS: 80,304 B total -> 2 blocks/CU
  __shared__ __align__(16) char qtreg[2 * 64 * KP * 2];      // 34,816 B (qT chunk | hmpart alias)
  __shared__ __align__(16) ushort pAm[4][16 * KP];            // 17,408 B
  __shared__ __align__(16) char dreg[2 * 16 * DP * 2];        // 25,088 B
  __shared__ float2 w2pk[HH];                                 // 800 B
  __shared__ float qlast[HH];                                 // 400 B
  __shared__ float ps_s[IB][6];                               // 384 B
  __shared__ float stats_s[4][IB][5];                         // 1,280 B
  __shared__ float sgn_s[IB];                                 // 64 B
  __shared__ int aidxs[IB];                                   // 64 B

  ushort* qTh = (ushort*)qtreg;
  ushort* qTl = qTh + 64 * KP;
  float*  hmpart = (float*)qtreg;       // [4][16][116] after pass 1
  ushort* d_hi = (ushort*)dreg;
  ushort* d_lo = d_hi + 16 * DP;

  const int blk = blockIdx.x;
  const int nib = SS / IB;              // 24
  const int dir = blk / (BB * nib);
  const int rem = blk % (BB * nib);
  const int b   = rem / nib;
  const int i0  = (rem % nib) * IB;

  const float* __restrict__ p  = dir ? pb  : pf;
  const float* __restrict__ q  = dir ? qb  : qf;
  const float* __restrict__ w1 = dir ? w1b : w1f;
  const float* __restrict__ w2 = dir ? w2b : w2f;

  const int t  = threadIdx.x;
  const int w  = t >> 6;
  const int lane = t & 63;
  const int li = lane & 15;
  const int lg = lane >> 4;
  const size_t AS = (size_t)SS * BB * 2;
  const float* __restrict__ qrow0 = q + (size_t)b * SS;

  // ---- stage weights ----
  if (t < HH) {
    float a0 = w2[t], a1 = w2[HH + t];
    w2pk[t] = make_float2(a0 * a0, a1 * a1);
    qlast[t] = q[(size_t)t * BB * SS + (size_t)b * SS + (SS - 1)];
  }
  __syncthreads();

  // ---- build pA mats (0:p_hi 1:p_lo 2:(w2a^2 p)_hi 3:(w2b^2 p)_hi), zero-padded ----
  for (int e = t; e < 16 * KP; e += 256) {
    int i = e / KP, hp = e % KP;
    float x = 0.f, xga = 0.f, xgb = 0.f;
    if (hp < HH) {
      x = p[(size_t)hp * BB * SS + (size_t)b * SS + i0 + i];
      float2 wv = w2pk[hp];
      xga = x * wv.x; xgb = x * wv.y;
    }
    ushort hi = f2bf(x);
    pAm[0][e] = hi;
    pAm[1][e] = f2bf(x - bf2f(hi));
    pAm[2][e] = f2bf(xga);
    pAm[3][e] = f2bf(xgb);
  }

  // ---- psm1: per-row p-norm recips + m1 outputs ----
  {
    const int row = t >> 4, hl = t & 15;
    float ps0=0,ps1=0,ps2=0,ps3=0,ps4=0,ps5=0,ps6=0,ps7=0;
    float m1n0=0,m1n1=0,nq1a=0,nq1b=0;
    for (int h = hl; h < HH; h += 16) {
      float pv = p[(size_t)h * BB * SS + (size_t)b * SS + i0 + row];
      float ql = qlast[h];
      float p2 = pv * pv, q2 = ql * ql, pq = pv * ql;
      float w1a = w1[h], w1bv = w1[HH + h];
      float w3a = w3f_[h], w3b = w3f_[HH + h];
      float w4a = w4f_[h], w4b = w4f_[HH + h];
      float2 w2v = w2pk[h];
      float w10 = w1a * w1a, w11 = w1bv * w1bv;
      ps0 = fmaf(w10, p2, ps0);       ps1 = fmaf(w11, p2, ps1);
      ps2 = fmaf(w2v.x, p2, ps2);     ps3 = fmaf(w2v.y, p2, ps3);
      ps4 = fmaf(w3a * w3a, p2, ps4); ps5 = fmaf(w3b * w3b, p2, ps5);
      ps6 = fmaf(w4a * w4a, p2, ps6); ps7 = fmaf(w4b * w4b, p2, ps7);
      m1n0 = fmaf(w10, pq, m1n0);     m1n1 = fmaf(w11, pq, m1n1);
      nq1a = fmaf(w10, q2, nq1a);     nq1b = fmaf(w11, q2, nq1b);
    }
#pragma unroll
    for (int m = 1; m < 16; m <<= 1) {
      ps0 += __shfl_xor(ps0, m, 16);  ps1 += __shfl_xor(ps1, m, 16);
      ps2 += __shfl_xor(ps2, m, 16);  ps3 += __shfl_xor(ps3, m, 16);
      ps4 += __shfl_xor(ps4, m, 16);  ps5 += __shfl_xor(ps5, m, 16);
      ps6 += __shfl_xor(ps6, m, 16);  ps7 += __shfl_xor(ps7, m, 16);
      m1n0 += __shfl_xor(m1n0, m, 16); m1n1 += __shfl_xor(m1n1, m, 16);
      nq1a += __shfl_xor(nq1a, m, 16); nq1b += __shfl_xor(nq1b, m, 16);
    }
    if (hl == 0) {
      const size_t base = (size_t)(i0 + row) * (BB * 2) + (size_t)b * 2;
      out[(size_t)(0 + dir) * AS + base + 0] =
          m1n0 / (fmaxf(sqrtf(ps0), EPSF) * fmaxf(sqrtf(nq1a), EPSF));
      out[(size_t)(0 + dir) * AS + base + 1] =
          m1n1 / (fmaxf(sqrtf(ps1), EPSF) * fmaxf(sqrtf(nq1b), EPSF));
      ps_s[row][0] = 1.0f / fmaxf(sqrtf(ps2), EPSF);
      ps_s[row][1] = 1.0f / fmaxf(sqrtf(ps3), EPSF);
      ps_s[row][2] = 1.0f / fmaxf(sqrtf(ps4), EPSF);
      ps_s[row][3] = 1.0f / fmaxf(sqrtf(ps5), EPSF);
      ps_s[row][4] = 1.0f / fmaxf(sqrtf(ps6), EPSF);
      ps_s[row][5] = 1.0f / fmaxf(sqrtf(ps7), EPSF);
    }
  }
  __syncthreads();

  // ---- Pass 1: gram via MFMA (att hi/lo 3-term; ga/gb hi) ----
  f32x4 attD = {0.f,0.f,0.f,0.f}, gaD = {0.f,0.f,0.f,0.f}, gbD = {0.f,0.f,0.f,0.f};
  float rowsum[4] = {0,0,0,0};
  float amax[4] = {-INFINITY,-INFINITY,-INFINITY,-INFINITY};
  int   aidx[4] = {0,0,0,0};
  float m2a[4] = {-INFINITY,-INFINITY,-INFINITY,-INFINITY};
  float m2b[4] = {-INFINITY,-INFINITY,-INFINITY,-INFINITY};

  const float* nqa = nq2ws + ((size_t)(dir * 2 + 0) * BB + b) * SS;
  const float* nqb = nq2ws + ((size_t)(dir * 2 + 1) * BB + b) * SS;
  const float* nqp = nq2ws + ((size_t)(4 + dir) * BB + b) * SS;

  for (int jc = 0; jc < 6; ++jc) {
    // stage qT chunk (64 j x KP), linear copy
    {
      const size_t cb = ((size_t)(dir * BB + b) * SS + jc * 64) * KP;
      const uint4* s0 = (const uint4*)(qTg_hi + cb);
      const uint4* s1 = (const uint4*)(qTg_lo + cb);
      uint4* dh = (uint4*)qTh;
      uint4* dl = (uint4*)qTl;
      for (int it = t; it < 1088; it += 256) dh[it] = s0[it];
      for (int it = t; it < 1088; it += 256) dl[it] = s1[it];
    }
    __syncthreads();
#pragma unroll
    for (int kt = 0; kt < 4; ++kt) {
      const int ao = li * KP + kt * 32 + 8 * lg;
      const int bo = (w * 16 + li) * KP + kt * 32 + 8 * lg;
      bf16x8 aHi = *(const bf16x8*)&pAm[0][ao];
      bf16x8 aLo = *(const bf16x8*)&pAm[1][ao];
      bf16x8 aGa = *(const bf16x8*)&pAm[2][ao];
      bf16x8 aGb = *(const bf16x8*)&pAm[3][ao];
      bf16x8 bHi = *(const bf16x8*)&qTh[bo];
      bf16x8 bLo = *(const bf16x8*)&qTl[bo];
      attD = __builtin_amdgcn_mfma_f32_16x16x32_bf16(aHi, bHi, attD, 0, 0, 0);
      attD = __builtin_amdgcn_mfma_f32_16x16x32_bf16(aLo, bHi, attD, 0, 0, 0);
      attD = __builtin_amdgcn_mfma_f32_16x16x32_bf16(aHi, bLo, attD, 0, 0, 0);
      gaD  = __builtin_amdgcn_mfma_f32_16x16x32_bf16(aGa, bHi, gaD, 0, 0, 0);
      gbD  = __builtin_amdgcn_mfma_f32_16x16x32_bf16(aGb, bHi, gbD, 0, 0, 0);
    }
    const int j = jc * 64 + w * 16 + li;
    const float rp = nqp[j], ra = nqa[j], rb = nqb[j];
#pragma unroll
    for (int r = 0; r < 4; ++r) {
      float d = attD[r] * rp;
      int row = lg * 4 + r;
      rowsum[r] += d;
      if (d > amax[r]) { amax[r] = d; aidx[r] = j; }
      m2a[r] = fmaxf(m2a[r], gaD[r] * ra);
      m2b[r] = fmaxf(m2b[r], gbD[r] * rb);
      ushort hi = f2bf(d);
      d_hi[row * DP + j] = hi;
      d_lo[row * DP + j] = f2bf(d - bf2f(hi));
      attD[r] = 0.f; gaD[r] = 0.f; gbD[r] = 0.f;
    }
    __syncthreads();
  }

  // ---- stat reduce (within 16-lane j-groups), then cross-wave ----
#pragma unroll
  for (int m = 1; m < 16; m <<= 1) {
#pragma unroll
    for (int r = 0; r < 4; ++r) {
      rowsum[r] += __shfl_xor(rowsum[r], m);
      float ov = __shfl_xor(amax[r], m);
      int   oi = __shfl_xor(aidx[r], m);
      if (ov > amax[r] || (ov == amax[r] && oi < aidx[r])) { amax[r] = ov; aidx[r] = oi; }
      m2a[r] = fmaxf(m2a[r], __shfl_xor(m2a[r], m));
      m2b[r] = fmaxf(m2b[r], __shfl_xor(m2b[r], m));
    }
  }
  if (li == 0) {
#pragma unroll
    for (int r = 0; r < 4; ++r) {
      int row = lg * 4 + r;
      stats_s[w][row][0] = rowsum[r];
      stats_s[w][row][1] = amax[r];
      stats_s[w][row][2] = __int_as_float(aidx[r]);
      stats_s[w][row][3] = m2a[r];
      stats_s[w][row][4] = m2b[r];
    }
  }
  __syncthreads();
  if (t < IB) {
    float rs = 0.f, am = -INFINITY, ma = -INFINITY, mb = -INFINITY;
    int ai = 0;
    for (int wv = 0; wv < 4; ++wv) {
      rs += stats_s[wv][t][0];
      float ov = stats_s[wv][t][1];
      int oi = __float_as_int(stats_s[wv][t][2]);
      if (ov > am || (ov == am && oi < ai)) { am = ov; ai = oi; }
      ma = fmaxf(ma, stats_s[wv][t][3]);
      mb = fmaxf(mb, stats_s[wv][t][4]);
    }
    sgn_s[t] = (rs < 0.f) ? -1.f : 1.f;
    aidxs[t] = ai;
    const size_t base = (size_t)(i0 + t) * (BB * 2) + (size_t)b * 2;
    out[(size_t)(2 + dir) * AS + base + 0] = ma * ps_s[t][0];
    out[(size_t)(2 + dir) * AS + base + 1] = mb * ps_s[t][1];
  }
  __syncthreads();   // qT region now free -> hmpart

  // ---- Pass 2: hm = d * q^T via MFMA (M=16 rows, N=h tiles, K=j) ----
  for (int nt = 0; nt < 7; ++nt) {
    f32x4 hmD = {0.f,0.f,0.f,0.f};
#pragma unroll
    for (int kk = 0; kk < 3; ++kk) {
      const int kt = w * 3 + kk;
      const int ao = li * DP + kt * 32 + 8 * lg;
      bf16x8 aHi = *(const bf16x8*)&d_hi[ao];
      bf16x8 aLo = *(const bf16x8*)&d_lo[ao];
      const size_t go = ((size_t)(dir * HP + nt * 16 + li) * BB + b) * SS + kt * 32 + 8 * lg;
      bf16x8 bHi = *(const bf16x8*)(qhj_hi + go);
      bf16x8 bLo = *(const bf16x8*)(qhj_lo + go);
      hmD = __builtin_amdgcn_mfma_f32_16x16x32_bf16(aHi, bHi, hmD, 0, 0, 0);
      hmD = __builtin_amdgcn_mfma_f32_16x16x32_bf16(aLo, bHi, hmD, 0, 0, 0);
      hmD = __builtin_amdgcn_mfma_f32_16x16x32_bf16(aHi, bLo, hmD, 0, 0, 0);
    }
#pragma unroll
    for (int r = 0; r < 4; ++r) {
      int i = lg * 4 + r;
      hmpart[((size_t)w * 16 + i) * 116 + nt * 16 + li] = hmD[r];
    }
  }
  __syncthreads();

  // ---- Final m3/m4 epilogue ----
  {
    const int row = t >> 4, hl = t & 15;
    const int ax = aidxs[row];
    const float sg = sgn_s[row];
    float m3n0=0,m3n1=0,nh0=0,nh1=0,m4n0=0,m4n1=0,nq4a=0,nq4b=0;
    for (int h = hl; h < HH; h += 16) {
      float hm = hmpart[(size_t)(0 * 16 + row) * 116 + h]
               + hmpart[(size_t)(1 * 16 + row) * 116 + h]
               + hmpart[(size_t)(2 * 16 + row) * 116 + h]
               + hmpart[(size_t)(3 * 16 + row) * 116 + h];
      float pv = p[(size_t)h * BB * SS + (size_t)b * SS + i0 + row];
      float qi = qrow0[(size_t)h * BB * SS + ax];
      float w3a = w3f_[h], w3b = w3f_[HH + h];
      float w4a = w4f_[h], w4b = w4f_[HH + h];
      float w30 = w3a * w3a, w31 = w3b * w3b;
      float w40 = w4a * w4a, w41 = w4b * w4b;
      m3n0 = fmaf(w30, pv * hm, m3n0);
      m3n1 = fmaf(w31, pv * hm, m3n1);
      nh0  = fmaf(w30, hm * hm, nh0);
      nh1  = fmaf(w31, hm * hm, nh1);
      m4n0 = fmaf(w40, pv * qi, m4n0);
      m4n1 = fmaf(w41, pv * qi, m4n1);
      nq4a = fmaf(w40, qi * qi, nq4a);
      nq4b = fmaf(w41, qi * qi, nq4b);
    }
#pragma unroll
    for (int m = 1; m < 16; m <<= 1) {
      m3n0 += __shfl_xor(m3n0, m, 16); m3n1 += __shfl_xor(m3n1, m, 16);
      nh0  += __shfl_xor(nh0,  m, 16); nh1  += __shfl_xor(nh1,  m, 16);
      m4n0 += __shfl_xor(m4n0, m, 16); m4n1 += __shfl_xor(m4n1, m, 16);
      nq4a += __shfl_xor(nq4a, m, 16); nq4b += __shfl_xor(nq4b, m, 16);
    }
    if (hl == 0) {
      const size_t base = (size_t)(i0 + row) * (BB * 2) + (size_t)b * 2;
      out[(size_t)(4 + dir) * AS + base + 0] =
          sg * m3n0 * ps_s[row][2] / fmaxf(sqrtf(nh0), EPSF);
      out[(size_t)(4 + dir) * AS + base + 1] =
          sg * m3n1 * ps_s[row][3] / fmaxf(sqrtf(nh1), EPSF);
      out[(size_t)(6 + dir) * AS + base + 0] =
          m4n0 * ps_s[row][4] / fmaxf(sqrtf(nq4a), EPSF);
      out[(size_t)(6 + dir) * AS + base + 1] =
          m4n1 * ps_s[row][5] / fmaxf(sqrtf(nq4b), EPSF);
    }
  }
}

// ================= Fallback (R4 VALU kernel) if ws too small =================
#define FIB 16
#define FHT 10
#define FJT 32
#define FJP 36
#define FPCP 18
__global__ __launch_bounds__(256) void bimpm_fb(
    const float* __restrict__ pf, const float* __restrict__ pb,
    const float* __restrict__ qf, const float* __restrict__ qb,
    const float* __restrict__ w1f, const float* __restrict__ w1b,
    const float* __restrict__ w2f, const float* __restrict__ w2b,
    const float* __restrict__ w3f_, const float* __restrict__ w4f_,
    const float* __restrict__ nq2ws, float* __restrict__ out)
{
  __shared__ __align__(16) float qbuf[FHT * SS];
  __shared__ __align__(16) float attn_s[FIB][SS];
  __shared__ __align__(16) float pcolT[HH * FPCP];
  __shared__ float2 w2pk[HH];
  __shared__ float qlast[HH];
  __shared__ float ps_s[FIB][6];
  __shared__ int aidx_s[FIB];

  const int blk = blockIdx.x;
  const int nib = SS / FIB;
  const int dir = blk / (BB * nib);
  const int rem = blk % (BB * nib);
  const int b   = rem / nib;
  const int i0  = (rem % nib) * FIB;

  const float* __restrict__ p  = dir ? pb  : pf;
  const float* __restrict__ q  = dir ? qb  : qf;
  const float* __restrict__ w1 = dir ? w1b : w1f;
  const float* __restrict__ w2 = dir ? w2b : w2f;

  const int t  = threadIdx.x;
  const int w  = t >> 6;
  const int l  = t & 63;
  const int hs = l >> 5;
  const int jg = l & 31;
  const int jbase = jg * 12;
  const int lr0 = w * 4 + hs * 2;
  const size_t AS = (size_t)SS * BB * 2;

  if (t < HH) {
    float a0 = w2[t], a1 = w2[HH + t];
    w2pk[t] = make_float2(a0 * a0, a1 * a1);
    qlast[t] = q[(size_t)t * BB * SS + (size_t)b * SS + (SS - 1)];
  }
  for (int e = t; e < HH * FIB; e += 256) {
    int h = e >> 4, ii = e & 15;
    pcolT[h * FPCP + ii] = p[(size_t)h * BB * SS + (size_t)b * SS + i0 + ii];
  }
  __syncthreads();
  const float* __restrict__ qrow0 = q + (size_t)b * SS;
  {
    const int row = t >> 4, hl = t & 15;
    float ps0=0,ps1=0,ps2=0,ps3=0,ps4=0,ps5=0,ps6=0,ps7=0;
    float m1n0=0,m1n1=0,nq1a=0,nq1b=0;
    for (int h = hl; h < HH; h += 16) {
      float pv = pcolT[h * FPCP + row];
      float ql = qlast[h];
      float p2 = pv * pv, q2 = ql * ql, pq = pv * ql;
      float w1a = w1[h], w1bv = w1[HH + h];
      float w3a = w3f_[h], w3b = w3f_[HH + h];
      float w4a = w4f_[h], w4b = w4f_[HH + h];
      float2 w2v = w2pk[h];
      float w10 = w1a * w1a, w11 = w1bv * w1bv;
      ps0 = fmaf(w10, p2, ps0);       ps1 = fmaf(w11, p2, ps1);
      ps2 = fmaf(w2v.x, p2, ps2);     ps3 = fmaf(w2v.y, p2, ps3);
      ps4 = fmaf(w3a * w3a, p2, ps4); ps5 = fmaf(w3b * w3b, p2, ps5);
      ps6 = fmaf(w4a * w4a, p2, ps6); ps7 = fmaf(w4b * w4b, p2, ps7);
      m1n0 = fmaf(w10, pq, m1n0);     m1n1 = fmaf(w11, pq, m1n1);
      nq1a = fmaf(w10, q2, nq1a);     nq1b = fmaf(w11, q2, nq1b);
    }
#pragma unroll
    for (int m = 1; m < 16; m <<= 1) {
      ps0 += __shfl_xor(ps0, m, 16);  ps1 += __shfl_xor(ps1, m, 16);
      ps2 += __shfl_xor(ps2, m, 16);  ps3 += __shfl_xor(ps3, m, 16);
      ps4 += __shfl_xor(ps4, m, 16);  ps5 += __shfl_xor(ps5, m, 16);
      ps6 += __shfl_xor(ps6, m, 16);  ps7 += __shfl_xor(ps7, m, 16);
      m1n0 += __shfl_xor(m1n0, m, 16); m1n1 += __shfl_xor(m1n1, m, 16);
      nq1a += __shfl_xor(nq1a, m, 16); nq1b += __shfl_xor(nq1b, m, 16);
    }
    if (hl == 0) {
      const size_t base = (size_t)(i0 + row) * (BB * 2) + (size_t)b * 2;
      out[(size_t)(0 + dir) * AS + base + 0] =
          m1n0 / (fmaxf(sqrtf(ps0), EPSF) * fmaxf(sqrtf(nq1a), EPSF));
      out[(size_t)(0 + dir) * AS + base + 1] =
          m1n1 / (fmaxf(sqrtf(ps1), EPSF) * fmaxf(sqrtf(nq1b), EPSF));
      ps_s[row][0] = 1.0f / fmaxf(sqrtf(ps2), EPSF);
      ps_s[row][1] = 1.0f / fmaxf(sqrtf(ps3), EPSF);
      ps_s[row][2] = 1.0f / fmaxf(sqrtf(ps4), EPSF);
      ps_s[row][3] = 1.0f / fmaxf(sqrtf(ps5), EPSF);
      ps_s[row][4] = 1.0f / fmaxf(sqrtf(ps6), EPSF);
      ps_s[row][5] = 1.0f / fmaxf(sqrtf(ps7), EPSF);
    }
  }
  float att[2][12], ga[2][12], gb[2][12];
#pragma unroll
  for (int r = 0; r < 2; ++r)
#pragma unroll
    for (int k = 0; k < 12; ++k) { att[r][k] = 0.f; ga[r][k] = 0.f; gb[r][k] = 0.f; }
  for (int ht = 0; ht < 10; ++ht) {
    const int h0 = ht * FHT;
    __syncthreads();
#pragma unroll
    for (int k = 0; k < 4; ++k) {
      int e = t + k * 256;
      if (e < (FHT * SS) / 4) {
        int hh = e / (SS / 4), qd = e % (SS / 4);
        float4 v = *(const float4*)&qrow0[(size_t)(h0 + hh) * BB * SS + qd * 4];
        *(float4*)&qbuf[hh * SS + qd * 4] = v;
      }
    }
    __syncthreads();
#pragma unroll
    for (int hh = 0; hh < FHT; ++hh) {
      const int h = h0 + hh;
      const float2 pT = *(const float2*)&pcolT[h * FPCP + lr0];
      const float2 w2v = w2pk[h];
      const float pa0 = pT.x * w2v.x, pb0 = pT.x * w2v.y;
      const float pa1 = pT.y * w2v.x, pb1 = pT.y * w2v.y;
      const float4* qr = (const float4*)&qbuf[hh * SS + jbase];
#pragma unroll
      for (int kk = 0; kk < 3; ++kk) {
        float4 qv = qr[kk];
        float qe[4] = {qv.x, qv.y, qv.z, qv.w};
#pragma unroll
        for (int c = 0; c < 4; ++c) {
          int k = kk * 4 + c;
          att[0][k] = fmaf(pT.x, qe[c], att[0][k]);
          att[1][k] = fmaf(pT.y, qe[c], att[1][k]);
          ga[0][k]  = fmaf(pa0,  qe[c], ga[0][k]);
          ga[1][k]  = fmaf(pa1,  qe[c], ga[1][k]);
          gb[0][k]  = fmaf(pb0,  qe[c], gb[0][k]);
          gb[1][k]  = fmaf(pb1,  qe[c], gb[1][k]);
        }
      }
    }
  }
  {
    const float* nqa = nq2ws + ((size_t)(dir * 2 + 0) * BB + b) * SS + jbase;
    const float* nqb = nq2ws + ((size_t)(dir * 2 + 1) * BB + b) * SS + jbase;
    const float* nqp = nq2ws + ((size_t)(4 + dir) * BB + b) * SS + jbase;
    float ra[12], rb[12], rp[12];
#pragma unroll
    for (int kk = 0; kk < 3; ++kk) {
      float4 va = ((const float4*)nqa)[kk];
      float4 vb = ((const float4*)nqb)[kk];
      float4 vp = ((const float4*)nqp)[kk];
      ra[kk*4+0]=va.x; ra[kk*4+1]=va.y; ra[kk*4+2]=va.z; ra[kk*4+3]=va.w;
      rb[kk*4+0]=vb.x; rb[kk*4+1]=vb.y; rb[kk*4+2]=vb.z; rb[kk*4+3]=vb.w;
      rp[kk*4+0]=vp.x; rp[kk*4+1]=vp.y; rp[kk*4+2]=vp.z; rp[kk*4+3]=vp.w;
    }
#pragma unroll
    for (int r = 0; r < 2; ++r) {
      float rowsum = 0.f;
      float amax = -INFINITY; int aidx = 0;
      float m2a = -INFINITY, m2b = -INFINITY;
#pragma unroll
      for (int k = 0; k < 12; ++k) {
        float d = att[r][k] * rp[k];
        att[r][k] = d;
        rowsum += d;
        if (d > amax) { amax = d; aidx = jbase + k; }
        m2a = fmaxf(m2a, ga[r][k] * ra[k]);
        m2b = fmaxf(m2b, gb[r][k] * rb[k]);
      }
#pragma unroll
      for (int m = 1; m < 32; m <<= 1) {
        rowsum += __shfl_xor(rowsum, m, 32);
        float ov = __shfl_xor(amax, m, 32);
        int   oi = __shfl_xor(aidx, m, 32);
        if (ov > amax || (ov == amax && oi < aidx)) { amax = ov; aidx = oi; }
        m2a = fmaxf(m2a, __shfl_xor(m2a, m, 32));
        m2b = fmaxf(m2b, __shfl_xor(m2b, m, 32));
      }
      const int lr = lr0 + r;
      const float inv_rs = 1.0f / rowsum;
      *(float4*)&attn_s[lr][jbase + 0] =
          make_float4(att[r][0]*inv_rs, att[r][1]*inv_rs, att[r][2]*inv_rs, att[r][3]*inv_rs);
      *(float4*)&attn_s[lr][jbase + 4] =
          make_float4(att[r][4]*inv_rs, att[r][5]*inv_rs, att[r][6]*inv_rs, att[r][7]*inv_rs);
      *(float4*)&attn_s[lr][jbase + 8] =
          make_float4(att[r][8]*inv_rs, att[r][9]*inv_rs, att[r][10]*inv_rs, att[r][11]*inv_rs);
      if (jg == 0) {
        aidx_s[lr] = aidx;
        const size_t base = (size_t)(i0 + lr) * (BB * 2) + (size_t)b * 2;
        out[(size_t)(2 + dir) * AS + base + 0] = m2a * ps_s[lr][0];
        out[(size_t)(2 + dir) * AS + base + 1] = m2b * ps_s[lr][1];
      }
    }
  }
  const int grp  = t >> 7;
  const int hown = t & 127;
  float hv[FIB];
#pragma unroll
  for (int r = 0; r < FIB; ++r) hv[r] = 0.f;
  for (int jt = 0; jt < 12; ++jt) {
    const int j0 = jt * FJT;
    __syncthreads();
#pragma unroll
    for (int k = 0; k < 4; ++k) {
      int e = t + k * 256;
      if (e < HH * (FJT / 4)) {
        int hh = e >> 3, qd = e & 7;
        float4 v = *(const float4*)&qrow0[(size_t)hh * BB * SS + j0 + qd * 4];
        *(float4*)&qbuf[hh * FJP + qd * 4] = v;
      }
    }
    __syncthreads();
    if (hown < HH) {
      const float* qrowL = &qbuf[hown * FJP];
#pragma unroll
      for (int qd2 = 0; qd2 < 4; ++qd2) {
        const int qd = grp * 4 + qd2;
        float4 qv = *(const float4*)&qrowL[qd * 4];
#pragma unroll
        for (int r = 0; r < FIB; ++r) {
          float4 av = *(const float4*)&attn_s[r][j0 + qd * 4];
          hv[r] = fmaf(av.x, qv.x, fmaf(av.y, qv.y, fmaf(av.z, qv.z, fmaf(av.w, qv.w, hv[r]))));
        }
      }
    }
  }
  __syncthreads();
  if (hown < HH) {
#pragma unroll
    for (int r = 0; r < FIB; ++r) qbuf[grp * (FIB * HH) + r * HH + hown] = hv[r];
  }
  __syncthreads();
  {
    const int row = t >> 4, hl = t & 15;
    const int ax = aidx_s[row];
    float m3n0=0,m3n1=0,nh0=0,nh1=0,m4n0=0,m4n1=0,nq4a=0,nq4b=0;
    for (int h = hl; h < HH; h += 16) {
      float hm = qbuf[row * HH + h] + qbuf[FIB * HH + row * HH + h];
      float pv = pcolT[h * FPCP + row];
      float qi = qrow0[(size_t)h * BB * SS + ax];
      float w3a = w3f_[h], w3b = w3f_[HH + h];
      float w4a = w4f_[h], w4b = w4f_[HH + h];
      float w30 = w3a * w3a, w31 = w3b * w3b;
      float w40 = w4a * w4a, w41 = w4b * w4b;
      m3n0 = fmaf(w30, pv * hm, m3n0);
      m3n1 = fmaf(w31, pv * hm, m3n1);
      nh0  = fmaf(w30, hm * hm, nh0);
      nh1  = fmaf(w31, hm * hm, nh1);
      m4n0 = fmaf(w40, pv * qi, m4n0);
      m4n1 = fmaf(w41, pv * qi, m4n1);
      nq4a = fmaf(w40, qi * qi, nq4a);
      nq4b = fmaf(w41, qi * qi, nq4b);
    }
#pragma unroll
    for (int m = 1; m < 16; m <<= 1) {
      m3n0 += __shfl_xor(m3n0, m, 16); m3n1 += __shfl_xor(m3n1, m, 16);
      nh0  += __shfl_xor(nh0,  m, 16); nh1  += __shfl_xor(nh1,  m, 16);
      m4n0 += __shfl_xor(m4n0, m, 16); m4n1 += __shfl_xor(m4n1, m, 16);
      nq4a += __shfl_xor(nq4a, m, 16); nq4b += __shfl_xor(nq4b, m, 16);
    }
    if (hl == 0) {
      const size_t base = (size_t)(i0 + row) * (BB * 2) + (size_t)b * 2;
      out[(size_t)(4 + dir) * AS + base + 0] =
          m3n0 * ps_s[row][2] / fmaxf(sqrtf(nh0), EPSF);
      out[(size_t)(4 + dir) * AS + base + 1] =
          m3n1 * ps_s[row][3] / fmaxf(sqrtf(nh1), EPSF);
      out[(size_t)(6 + dir) * AS + base + 0] =
          m4n0 * ps_s[row][4] / fmaxf(sqrtf(nq4a), EPSF);
      out[(size_t)(6 + dir) * AS + base + 1] =
          m4n1 * ps_s[row][5] / fmaxf(sqrtf(nq4b), EPSF);
    }
  }
}

extern "C" void kernel_launch(void* const* d_in, const int* in_sizes, int n_in,
                              void* d_out, int out_size, void* d_ws, size_t ws_size,
                              hipStream_t stream) {
  const float* pf  = (const float*)d_in[0];
  const float* pb  = (const float*)d_in[1];
  const float* qf  = (const float*)d_in[2];
  const float* qb  = (const float*)d_in[3];
  const float* w1f = (const float*)d_in[4];
  const float* w1b = (const float*)d_in[5];
  const float* w2f = (const float*)d_in[6];
  const float* w2b = (const float*)d_in[7];
  const float* w3f = (const float*)d_in[8];
  const float* w4f = (const float*)d_in[10];  // w3b/w4b unused by reference
  float* out = (float*)d_out;

  // ws layout
  const size_t nq2_b   = (size_t)6 * BB * SS * 4;            //    589,824
  const size_t qhj_b   = (size_t)2 * HP * BB * SS * 2;       // 11,010,048
  const size_t qT_b    = (size_t)2 * BB * SS * KP * 2;       // 13,369,344
  const size_t NEEDED  = nq2_b + 2 * qhj_b + 2 * qT_b;       // 49,348,608

  float*  nq2    = (float*)d_ws;
  char*   base   = (char*)d_ws + nq2_b;
  ushort* qhj_hi = (ushort*)base;
  ushort* qhj_lo = (ushort*)(base + qhj_b);
  ushort* qT_hi  = (ushort*)(base + 2 * qhj_b);
  ushort* qT_lo  = (ushort*)(base + 2 * qhj_b + qT_b);

  hipLaunchKernelGGL(qnorm_kernel, dim3((2 * BB * SS + 255) / 256), dim3(256), 0, stream,
                     qf, qb, w2f, w2b, nq2);

  if (ws_size >= NEEDED) {
    hipLaunchKernelGGL(qsplit_kernel, dim3((2 * HP * BB * SS) / 256), dim3(256), 0, stream,
                       qf, qb, qhj_hi, qhj_lo);
    hipLaunchKernelGGL(qtbuild_kernel, dim3(2 * BB), dim3(256), 0, stream,
                       qf, qb, qT_hi, qT_lo);
    hipLaunchKernelGGL(bimpm_mfma, dim3(2 * BB * (SS / IB)), dim3(256), 0, stream,
                       pf, pb, qf, qb, w1f, w1b, w2f, w2b, w3f, w4f, nq2,
                       qhj_hi, qhj_lo, qT_hi, qT_lo, out);
  } else {
    hipLaunchKernelGGL(bimpm_fb, dim3(2 * BB * (SS / FIB)), dim3(256), 0, stream,
                       pf, pb, qf, qb, w1f, w1b, w2f, w2b, w3f, w4f, nq2, out);
  }
}

// Round 6
// 163.714 us; speedup vs baseline: 4.6770x; 2.0005x over previous
//
#include <hip/hip_runtime.h>
#include <math.h>

#define HH 100
#define HP 112
#define KP 136
#define BB 64
#define SS 384
#define EPSF 1e-6f
#define NCHUNK 12
#define CJ 32
#define CHUNK_USH (2 * CJ * KP)   // 8704 ushorts (hi block + lo block)
#define CHUNK_B   (CHUNK_USH * 2) // 17408 B

typedef __attribute__((ext_vector_type(8))) short bf16x8;
typedef __attribute__((ext_vector_type(4))) float f32x4;
typedef unsigned short ushort_t;

__device__ __forceinline__ ushort_t f2bf(float x) {
  unsigned u = __float_as_uint(x);
  unsigned r = (u + 0x7FFFu + ((u >> 16) & 1u)) >> 16;
  return (ushort_t)r;
}
__device__ __forceinline__ float bf2f(ushort_t h) {
  return __uint_as_float(((unsigned)h) << 16);
}

// ---------------- Prep kernel: norms + qhj split + qT chunks, one pass ----------------
__global__ __launch_bounds__(256) void qprep_kernel(
    const float* __restrict__ qf, const float* __restrict__ qb,
    const float* __restrict__ w2f, const float* __restrict__ w2b,
    float* __restrict__ nq2, ushort_t* __restrict__ qhj_hi,
    ushort_t* __restrict__ qhj_lo, ushort_t* __restrict__ qTil)
{
  __shared__ __align__(16) float tile[HH * 68];
  __shared__ float w2sq_s[HH][2];
  const int blk = blockIdx.x;
  const int dir = blk / (BB * 6);
  const int rem = blk % (BB * 6);
  const int b   = rem / 6;
  const int jt  = rem % 6;
  const int j0  = jt * 64;
  const float* q  = dir ? qb : qf;
  const float* w2 = dir ? w2b : w2f;
  const int t = threadIdx.x;
  if (t < HH) {
    float a = w2[t], c = w2[HH + t];
    w2sq_s[t][0] = a * a; w2sq_s[t][1] = c * c;
  }
  for (int e = t; e < HH * 16; e += 256) {
    int h = e >> 4, j4 = e & 15;
    float4 v = *(const float4*)&q[((size_t)h * BB + b) * SS + j0 + j4 * 4];
    *(float4*)&tile[h * 68 + j4 * 4] = v;
  }
  __syncthreads();
  // qT chunk-interleaved writes: [dir][b][chunk][hi|lo][jl][kp]
  for (int e = t; e < 64 * KP; e += 256) {
    int jj = e / KP, kp = e % KP;
    float x = (kp < HH) ? tile[kp * 68 + jj] : 0.f;
    ushort_t hi = f2bf(x);
    int cg = jt * 2 + (jj >> 5);
    size_t base = ((size_t)(dir * BB + b) * NCHUNK + cg) * CHUNK_USH
                + (size_t)(jj & 31) * KP + kp;
    qTil[base] = hi;
    qTil[base + CJ * KP] = f2bf(x - bf2f(hi));
  }
  // qhj hi/lo, zero-padded h in [100,112)
  for (int e = t; e < HP * 64; e += 256) {
    int hp = e >> 6, jj = e & 63;
    float x = (hp < HH) ? tile[hp * 68 + jj] : 0.f;
    ushort_t hi = f2bf(x);
    size_t o = ((size_t)(dir * HP + hp) * BB + b) * SS + j0 + jj;
    qhj_hi[o] = hi;
    qhj_lo[o] = f2bf(x - bf2f(hi));
  }
  // reciprocal norms for these 64 j
  if (t < 64) {
    float s0 = 0.f, s1 = 0.f, sp = 0.f;
    for (int h = 0; h < HH; ++h) {
      float v = tile[h * 68 + t];
      float v2 = v * v;
      s0 = fmaf(w2sq_s[h][0], v2, s0);
      s1 = fmaf(w2sq_s[h][1], v2, s1);
      sp += v2;
    }
    int j = j0 + t;
    nq2[((size_t)(dir * 2 + 0) * BB + b) * SS + j] = 1.0f / fmaxf(sqrtf(s0), EPSF);
    nq2[((size_t)(dir * 2 + 1) * BB + b) * SS + j] = 1.0f / fmaxf(sqrtf(s1), EPSF);
    nq2[((size_t)(4 + dir) * BB + b) * SS + j]     = 1.0f / fmaxf(sqrtf(sp), EPSF);
  }
}

// ---------------- Main fused kernel ----------------
__global__ __launch_bounds__(256) void bimpm_fused(
    const float* __restrict__ pf, const float* __restrict__ pb,
    const float* __restrict__ qf, const float* __restrict__ qb,
    const float* __restrict__ w1f, const float* __restrict__ w1b,
    const float* __restrict__ w2f, const float* __restrict__ w2b,
    const float* __restrict__ w3f_, const float* __restrict__ w4f_,
    const float* __restrict__ nq2ws,
    const ushort_t* __restrict__ qhj_hi, const ushort_t* __restrict__ qhj_lo,
    const ushort_t* __restrict__ qTil,
    float* __restrict__ out)
{
  // smem[0..29696): qTs (17408 B) during main loop; hmbuf [4][16][116] after
  __shared__ __align__(16) char smem[29696 + 8704];
  __shared__ __align__(16) float wsq[HH][8];
  __shared__ float qlast_s[HH];
  __shared__ float statb[4][16][4];

  ushort_t* qTs  = (ushort_t*)smem;
  float* bounce  = (float*)(smem + 29696);   // [4][544] (16 rows x 34 pitch)
  float* hmbuf   = (float*)smem;             // [4][16][116]

  const int blk = blockIdx.x;
  const int dir = blk / (BB * 6);
  const int rem = blk % (BB * 6);
  const int b   = rem / 6;
  const int i0  = (rem % 6) * 64;
  const float* __restrict__ p  = dir ? pb : pf;
  const float* __restrict__ q  = dir ? qb : qf;
  const float* __restrict__ w1 = dir ? w1b : w1f;
  const float* __restrict__ w2 = dir ? w2b : w2f;
  const int t = threadIdx.x;
  const int w = t >> 6, lane = t & 63, li = lane & 15, lg = lane >> 4;
  const int rowbase = i0 + w * 16;
  const size_t AS = (size_t)SS * BB * 2;
  const size_t qt_base = (size_t)(dir * BB + b) * NCHUNK * CHUNK_USH;

  if (t < HH) {
    float a, c;
    a = w1[t];   c = w1[HH + t];   wsq[t][0] = a*a; wsq[t][1] = c*c;
    a = w2[t];   c = w2[HH + t];   wsq[t][2] = a*a; wsq[t][3] = c*c;
    a = w3f_[t]; c = w3f_[HH + t]; wsq[t][4] = a*a; wsq[t][5] = c*c;
    a = w4f_[t]; c = w4f_[HH + t]; wsq[t][6] = a*a; wsq[t][7] = c*c;
    qlast_s[t] = q[(size_t)t * BB * SS + (size_t)b * SS + (SS - 1)];
  }
  // stage chunk 0 directly
  {
    const uint4* gs = (const uint4*)(qTil + qt_base);
    uint4* dsh = (uint4*)qTs;
    dsh[t] = gs[t]; dsh[t + 256] = gs[t + 256];
    dsh[t + 512] = gs[t + 512]; dsh[t + 768] = gs[t + 768];
    if (t < 64) dsh[t + 1024] = gs[t + 1024];
  }
  __syncthreads();

  // p fragments in registers: hi, lo, w2a^2*p (hi), w2b^2*p (hi)
  bf16x8 pHi[4], pLo[4], pGa[4], pGb[4];
#pragma unroll
  for (int kt = 0; kt < 4; ++kt) {
#pragma unroll
    for (int s = 0; s < 8; ++s) {
      int h = kt * 32 + 8 * lg + s;
      float pv = 0.f, ga = 0.f, gb = 0.f;
      if (h < HH) {
        pv = p[(size_t)h * BB * SS + (size_t)b * SS + rowbase + li];
        ga = pv * wsq[h][2];
        gb = pv * wsq[h][3];
      }
      ushort_t hi = f2bf(pv);
      pHi[kt][s] = (short)hi;
      pLo[kt][s] = (short)f2bf(pv - bf2f(hi));
      pGa[kt][s] = (short)f2bf(ga);
      pGb[kt][s] = (short)f2bf(gb);
    }
  }

  f32x4 hmD[7];
#pragma unroll
  for (int nt = 0; nt < 7; ++nt) hmD[nt] = (f32x4){0.f, 0.f, 0.f, 0.f};
  float rowsum[4] = {0, 0, 0, 0};
  float amax[4] = {-INFINITY, -INFINITY, -INFINITY, -INFINITY};
  float m2a[4] = {-INFINITY, -INFINITY, -INFINITY, -INFINITY};
  float m2b[4] = {-INFINITY, -INFINITY, -INFINITY, -INFINITY};
  int aidx[4] = {0, 0, 0, 0};
  const float* nqa = nq2ws + ((size_t)(dir * 2 + 0) * BB + b) * SS;
  const float* nqb = nq2ws + ((size_t)(dir * 2 + 1) * BB + b) * SS;
  const float* nqp = nq2ws + ((size_t)(4 + dir) * BB + b) * SS;
  float* bw = bounce + w * 544;

  for (int c = 0; c < NCHUNK; ++c) {
    // T14: issue next chunk's loads early (regs), write to LDS after barrier
    uint4 s0v, s1v, s2v, s3v, s4v;
    if (c + 1 < NCHUNK) {
      const uint4* gs = (const uint4*)(qTil + qt_base + (size_t)(c + 1) * CHUNK_USH);
      s0v = gs[t]; s1v = gs[t + 256]; s2v = gs[t + 512]; s3v = gs[t + 768];
      if (t < 64) s4v = gs[t + 1024];
    }
    const ushort_t* bufH = qTs;
    const ushort_t* bufL = qTs + CJ * KP;
    // ---- pass 1: two 16-j n-tiles ----
#pragma unroll
    for (int nn = 0; nn < 2; ++nn) {
      f32x4 attD = {0, 0, 0, 0}, gaD = {0, 0, 0, 0}, gbD = {0, 0, 0, 0};
#pragma unroll
      for (int kt = 0; kt < 4; ++kt) {
        const int bo = (nn * 16 + li) * KP + kt * 32 + 8 * lg;
        bf16x8 bHi = *(const bf16x8*)&bufH[bo];
        bf16x8 bLo = *(const bf16x8*)&bufL[bo];
        attD = __builtin_amdgcn_mfma_f32_16x16x32_bf16(pHi[kt], bHi, attD, 0, 0, 0);
        attD = __builtin_amdgcn_mfma_f32_16x16x32_bf16(pLo[kt], bHi, attD, 0, 0, 0);
        attD = __builtin_amdgcn_mfma_f32_16x16x32_bf16(pHi[kt], bLo, attD, 0, 0, 0);
        gaD  = __builtin_amdgcn_mfma_f32_16x16x32_bf16(pGa[kt], bHi, gaD, 0, 0, 0);
        gbD  = __builtin_amdgcn_mfma_f32_16x16x32_bf16(pGb[kt], bHi, gbD, 0, 0, 0);
      }
      const int j = c * CJ + nn * 16 + li;
      const float rp = nqp[j], ra = nqa[j], rb = nqb[j];
#pragma unroll
      for (int r = 0; r < 4; ++r) {
        float d = attD[r] * rp;
        rowsum[r] += d;
        if (d > amax[r]) { amax[r] = d; aidx[r] = j; }
        m2a[r] = fmaxf(m2a[r], gaD[r] * ra);
        m2b[r] = fmaxf(m2b[r], gbD[r] * rb);
        bw[(lg * 4 + r) * 34 + nn * 16 + li] = d;
      }
    }
    // ---- transpose d via per-wave bounce (wave-internal, no block barrier) ----
    asm volatile("s_waitcnt lgkmcnt(0)" ::: "memory");
    float4 v0 = *(const float4*)&bw[li * 34 + 8 * lg];
    float4 v1 = *(const float4*)&bw[li * 34 + 8 * lg + 4];
    bf16x8 dHi, dLo;
    {
      float vv[8] = {v0.x, v0.y, v0.z, v0.w, v1.x, v1.y, v1.z, v1.w};
#pragma unroll
      for (int s = 0; s < 8; ++s) {
        ushort_t hi = f2bf(vv[s]);
        dHi[s] = (short)hi;
        dLo[s] = (short)f2bf(vv[s] - bf2f(hi));
      }
    }
    // ---- pass 2: hm accumulation for this chunk's K range ----
#pragma unroll
    for (int nt = 0; nt < 7; ++nt) {
      const size_t go = ((size_t)(dir * HP + nt * 16 + li) * BB + b) * SS + c * CJ + 8 * lg;
      bf16x8 qHi = *(const bf16x8*)(qhj_hi + go);
      bf16x8 qLo = *(const bf16x8*)(qhj_lo + go);
      hmD[nt] = __builtin_amdgcn_mfma_f32_16x16x32_bf16(dHi, qHi, hmD[nt], 0, 0, 0);
      hmD[nt] = __builtin_amdgcn_mfma_f32_16x16x32_bf16(dLo, qHi, hmD[nt], 0, 0, 0);
      hmD[nt] = __builtin_amdgcn_mfma_f32_16x16x32_bf16(dHi, qLo, hmD[nt], 0, 0, 0);
    }
    __syncthreads();               // all waves done reading qTs
    if (c + 1 < NCHUNK) {
      uint4* dsh = (uint4*)qTs;
      dsh[t] = s0v; dsh[t + 256] = s1v; dsh[t + 512] = s2v; dsh[t + 768] = s3v;
      if (t < 64) dsh[t + 1024] = s4v;
      __syncthreads();             // next chunk staged
    }
  }

  // ---- stats reduce over li (rows are per-wave, no cross-wave reduce) ----
#pragma unroll
  for (int r = 0; r < 4; ++r) {
#pragma unroll
    for (int m = 1; m < 16; m <<= 1) {
      rowsum[r] += __shfl_xor(rowsum[r], m);
      float ov = __shfl_xor(amax[r], m);
      int   oi = __shfl_xor(aidx[r], m);
      if (ov > amax[r] || (ov == amax[r] && oi < aidx[r])) { amax[r] = ov; aidx[r] = oi; }
      m2a[r] = fmaxf(m2a[r], __shfl_xor(m2a[r], m));
      m2b[r] = fmaxf(m2b[r], __shfl_xor(m2b[r], m));
    }
  }
  if (li == 0) {
#pragma unroll
    for (int r = 0; r < 4; ++r) {
      const int row = lg * 4 + r;
      statb[w][row][0] = (rowsum[r] < 0.f) ? -1.f : 1.f;
      statb[w][row][1] = __int_as_float(aidx[r]);
      statb[w][row][2] = m2a[r];
      statb[w][row][3] = m2b[r];
    }
  }
  // hm to LDS (aliases qTs region; main loop fully barriered out)
#pragma unroll
  for (int nt = 0; nt < 7; ++nt) {
#pragma unroll
    for (int r = 0; r < 4; ++r) {
      hmbuf[(size_t)(w * 16 + lg * 4 + r) * 116 + nt * 16 + li] = hmD[nt][r];
    }
  }
  __syncthreads();

  // ---- epilogue: 4 lanes per row, all 8 outputs ----
  {
    const int row = lane & 15, hq = lane >> 4;
    const int gi = rowbase + row;
    const float sg   = statb[w][row][0];
    const int   ax   = __float_as_int(statb[w][row][1]);
    const float m2av = statb[w][row][2], m2bv = statb[w][row][3];
    float ps0=0,ps1=0,ps2=0,ps3=0,ps4=0,ps5=0,ps6=0,ps7=0;
    float m1n0=0,m1n1=0,nq1a=0,nq1b=0;
    float m3n0=0,m3n1=0,nh0=0,nh1=0;
    float m4n0=0,m4n1=0,nq4a=0,nq4b=0;
#pragma unroll 5
    for (int k = 0; k < 25; ++k) {
      int h = k * 4 + hq;   // covers 0..99 exactly
      float pv = p[(size_t)h * BB * SS + (size_t)b * SS + gi];
      float hm = hmbuf[(size_t)(w * 16 + row) * 116 + h];
      float ql = qlast_s[h];
      float qi = q[(size_t)h * BB * SS + (size_t)b * SS + ax];
      float4 wv0 = *(const float4*)&wsq[h][0];
      float4 wv1 = *(const float4*)&wsq[h][4];
      float p2 = pv * pv;
      ps0 = fmaf(wv0.x, p2, ps0); ps1 = fmaf(wv0.y, p2, ps1);
      ps2 = fmaf(wv0.z, p2, ps2); ps3 = fmaf(wv0.w, p2, ps3);
      ps4 = fmaf(wv1.x, p2, ps4); ps5 = fmaf(wv1.y, p2, ps5);
      ps6 = fmaf(wv1.z, p2, ps6); ps7 = fmaf(wv1.w, p2, ps7);
      m1n0 = fmaf(wv0.x, pv * ql, m1n0); m1n1 = fmaf(wv0.y, pv * ql, m1n1);
      nq1a = fmaf(wv0.x, ql * ql, nq1a); nq1b = fmaf(wv0.y, ql * ql, nq1b);
      m3n0 = fmaf(wv1.x, pv * hm, m3n0); m3n1 = fmaf(wv1.y, pv * hm, m3n1);
      nh0  = fmaf(wv1.x, hm * hm, nh0);  nh1  = fmaf(wv1.y, hm * hm, nh1);
      m4n0 = fmaf(wv1.z, pv * qi, m4n0); m4n1 = fmaf(wv1.w, pv * qi, m4n1);
      nq4a = fmaf(wv1.z, qi * qi, nq4a); nq4b = fmaf(wv1.w, qi * qi, nq4b);
    }
#pragma unroll
    for (int m = 16; m < 64; m <<= 1) {
      ps0 += __shfl_xor(ps0, m);  ps1 += __shfl_xor(ps1, m);
      ps2 += __shfl_xor(ps2, m);  ps3 += __shfl_xor(ps3, m);
      ps4 += __shfl_xor(ps4, m);  ps5 += __shfl_xor(ps5, m);
      ps6 += __shfl_xor(ps6, m);  ps7 += __shfl_xor(ps7, m);
      m1n0 += __shfl_xor(m1n0, m); m1n1 += __shfl_xor(m1n1, m);
      nq1a += __shfl_xor(nq1a, m); nq1b += __shfl_xor(nq1b, m);
      m3n0 += __shfl_xor(m3n0, m); m3n1 += __shfl_xor(m3n1, m);
      nh0  += __shfl_xor(nh0,  m); nh1  += __shfl_xor(nh1,  m);
      m4n0 += __shfl_xor(m4n0, m); m4n1 += __shfl_xor(m4n1, m);
      nq4a += __shfl_xor(nq4a, m); nq4b += __shfl_xor(nq4b, m);
    }
    if (hq == 0) {
      const size_t base = (size_t)gi * (BB * 2) + (size_t)b * 2;
      out[(size_t)(0 + dir) * AS + base + 0] =
          m1n0 / (fmaxf(sqrtf(ps0), EPSF) * fmaxf(sqrtf(nq1a), EPSF));
      out[(size_t)(0 + dir) * AS + base + 1] =
          m1n1 / (fmaxf(sqrtf(ps1), EPSF) * fmaxf(sqrtf(nq1b), EPSF));
      out[(size_t)(2 + dir) * AS + base + 0] = m2av / fmaxf(sqrtf(ps2), EPSF);
      out[(size_t)(2 + dir) * AS + base + 1] = m2bv / fmaxf(sqrtf(ps3), EPSF);
      out[(size_t)(4 + dir) * AS + base + 0] =
          sg * m3n0 / (fmaxf(sqrtf(ps4), EPSF) * fmaxf(sqrtf(nh0), EPSF));
      out[(size_t)(4 + dir) * AS + base + 1] =
          sg * m3n1 / (fmaxf(sqrtf(ps5), EPSF) * fmaxf(sqrtf(nh1), EPSF));
      out[(size_t)(6 + dir) * AS + base + 0] =
          m4n0 / (fmaxf(sqrtf(ps6), EPSF) * fmaxf(sqrtf(nq4a), EPSF));
      out[(size_t)(6 + dir) * AS + base + 1] =
          m4n1 / (fmaxf(sqrtf(ps7), EPSF) * fmaxf(sqrtf(nq4b), EPSF));
    }
  }
}

extern "C" void kernel_launch(void* const* d_in, const int* in_sizes, int n_in,
                              void* d_out, int out_size, void* d_ws, size_t ws_size,
                              hipStream_t stream) {
  const float* pf  = (const float*)d_in[0];
  const float* pb  = (const float*)d_in[1];
  const float* qf  = (const float*)d_in[2];
  const float* qb  = (const float*)d_in[3];
  const float* w1f = (const float*)d_in[4];
  const float* w1b = (const float*)d_in[5];
  const float* w2f = (const float*)d_in[6];
  const float* w2b = (const float*)d_in[7];
  const float* w3f = (const float*)d_in[8];
  const float* w4f = (const float*)d_in[10];  // w3b/w4b unused by reference
  float* out = (float*)d_out;

  const size_t nq2_b  = (size_t)6 * BB * SS * 4;            //    589,824
  const size_t qhj_b  = (size_t)2 * HP * BB * SS * 2;       // 11,010,048 each
  float*    nq2    = (float*)d_ws;
  ushort_t* qhj_hi = (ushort_t*)((char*)d_ws + nq2_b);
  ushort_t* qhj_lo = (ushort_t*)((char*)d_ws + nq2_b + qhj_b);
  ushort_t* qTil   = (ushort_t*)((char*)d_ws + nq2_b + 2 * qhj_b);  // 26,738,688 B

  hipLaunchKernelGGL(qprep_kernel, dim3(2 * BB * 6), dim3(256), 0, stream,
                     qf, qb, w2f, w2b, nq2, qhj_hi, qhj_lo, qTil);
  hipLaunchKernelGGL(bimpm_fused, dim3(2 * BB * 6), dim3(256), 0, stream,
                     pf, pb, qf, qb, w1f, w1b, w2f, w2b, w3f, w4f,
                     nq2, qhj_hi, qhj_lo, qTil, out);
}

// Round 7
// 162.429 us; speedup vs baseline: 4.7140x; 1.0079x over previous
//
#include <hip/hip_runtime.h>
#include <math.h>

#define HH 100
#define HP 112
#define KP 136
#define BB 64
#define SS 384
#define EPSF 1e-6f
#define NCHUNK 12
#define QT_USH 8704            // 2 * 32 * KP
#define QHJ_ROW 72             // ushorts/row: 4 slots x (hi8+lo8) + 8 pad
#define QHJ_USH (HP * QHJ_ROW) // 8064
#define BUF_USH (QT_USH + QHJ_USH)  // 16768 ushorts = 33536 B
#define BNC_PITCH 36

typedef __attribute__((ext_vector_type(8))) short bf16x8;
typedef __attribute__((ext_vector_type(4))) float f32x4;
typedef unsigned short ushort_t;

__device__ __forceinline__ ushort_t f2bf(float x) {
  unsigned u = __float_as_uint(x);
  unsigned r = (u + 0x7FFFu + ((u >> 16) & 1u)) >> 16;
  return (ushort_t)r;
}
__device__ __forceinline__ float bf2f(ushort_t h) {
  return __uint_as_float(((unsigned)h) << 16);
}

// ---------------- Prep kernel: norms + qhj split + qT chunks, one pass ----------------
__global__ __launch_bounds__(256) void qprep_kernel(
    const float* __restrict__ qf, const float* __restrict__ qb,
    const float* __restrict__ w2f, const float* __restrict__ w2b,
    float* __restrict__ nq2, ushort_t* __restrict__ qhj_hi,
    ushort_t* __restrict__ qhj_lo, ushort_t* __restrict__ qTil)
{
  __shared__ __align__(16) float tile[HH * 68];
  __shared__ float w2sq_s[HH][2];
  const int blk = blockIdx.x;
  const int dir = blk / (BB * 6);
  const int rem = blk % (BB * 6);
  const int b   = rem / 6;
  const int jt  = rem % 6;
  const int j0  = jt * 64;
  const float* q  = dir ? qb : qf;
  const float* w2 = dir ? w2b : w2f;
  const int t = threadIdx.x;
  if (t < HH) {
    float a = w2[t], c = w2[HH + t];
    w2sq_s[t][0] = a * a; w2sq_s[t][1] = c * c;
  }
  for (int e = t; e < HH * 16; e += 256) {
    int h = e >> 4, j4 = e & 15;
    float4 v = *(const float4*)&q[((size_t)h * BB + b) * SS + j0 + j4 * 4];
    *(float4*)&tile[h * 68 + j4 * 4] = v;
  }
  __syncthreads();
  // qT chunk-interleaved: [dir][b][chunk][hi 32xKP | lo 32xKP]
  for (int e = t; e < 64 * KP; e += 256) {
    int jj = e / KP, kp = e % KP;
    float x = (kp < HH) ? tile[kp * 68 + jj] : 0.f;
    ushort_t hi = f2bf(x);
    int cg = jt * 2 + (jj >> 5);
    size_t base = ((size_t)(dir * BB + b) * NCHUNK + cg) * QT_USH
                + (size_t)(jj & 31) * KP + kp;
    qTil[base] = hi;
    qTil[base + 32 * KP] = f2bf(x - bf2f(hi));
  }
  // qhj hi/lo, zero-padded h in [100,112)
  for (int e = t; e < HP * 64; e += 256) {
    int hp = e >> 6, jj = e & 63;
    float x = (hp < HH) ? tile[hp * 68 + jj] : 0.f;
    ushort_t hi = f2bf(x);
    size_t o = ((size_t)(dir * HP + hp) * BB + b) * SS + j0 + jj;
    qhj_hi[o] = hi;
    qhj_lo[o] = f2bf(x - bf2f(hi));
  }
  // reciprocal norms
  if (t < 64) {
    float s0 = 0.f, s1 = 0.f, sp = 0.f;
    for (int h = 0; h < HH; ++h) {
      float v = tile[h * 68 + t];
      float v2 = v * v;
      s0 = fmaf(w2sq_s[h][0], v2, s0);
      s1 = fmaf(w2sq_s[h][1], v2, s1);
      sp += v2;
    }
    int j = j0 + t;
    nq2[((size_t)(dir * 2 + 0) * BB + b) * SS + j] = 1.0f / fmaxf(sqrtf(s0), EPSF);
    nq2[((size_t)(dir * 2 + 1) * BB + b) * SS + j] = 1.0f / fmaxf(sqrtf(s1), EPSF);
    nq2[((size_t)(4 + dir) * BB + b) * SS + j]     = 1.0f / fmaxf(sqrtf(sp), EPSF);
  }
}

// ---------------- Main fused kernel ----------------
__global__ __launch_bounds__(256, 2) void bimpm_fused(
    const float* __restrict__ pf, const float* __restrict__ pb,
    const float* __restrict__ qf, const float* __restrict__ qb,
    const float* __restrict__ w1f, const float* __restrict__ w1b,
    const float* __restrict__ w2f, const float* __restrict__ w2b,
    const float* __restrict__ w3f_, const float* __restrict__ w4f_,
    const float* __restrict__ nq2ws,
    const ushort_t* __restrict__ qhj_hi, const ushort_t* __restrict__ qhj_lo,
    const ushort_t* __restrict__ qTil,
    float* __restrict__ out)
{
  // double-buffered chunk storage (qT + qhj); aliased by hmbuf after the loop
  __shared__ __align__(16) ushort_t smem[2 * BUF_USH];       // 67072 B
  __shared__ __align__(16) float bounce[4 * 16 * BNC_PITCH]; // 9216 B
  __shared__ __align__(16) float wsq[HH][8];                 // 3200 B
  __shared__ float qlast_s[HH];                              // 400 B
  __shared__ float statb[4][16][4];                          // 1024 B

  float* hmbuf = (float*)smem;   // [64][116] after main loop

  // XCD-aware work swizzle: 768 = 8 * 96, bijective
  const int bid  = blockIdx.x;
  const int work = (bid & 7) * 96 + (bid >> 3);
  const int dir = work / (BB * 6);
  const int rem = work % (BB * 6);
  const int b   = rem / 6;
  const int i0  = (rem % 6) * 64;

  const float* __restrict__ p  = dir ? pb : pf;
  const float* __restrict__ q  = dir ? qb : qf;
  const float* __restrict__ w1 = dir ? w1b : w1f;
  const float* __restrict__ w2 = dir ? w2b : w2f;
  const int t = threadIdx.x;
  const int w = t >> 6, lane = t & 63, li = lane & 15, lg = lane >> 4;
  const int rowbase = i0 + w * 16;
  const size_t AS = (size_t)SS * BB * 2;
  const size_t qt_base = (size_t)(dir * BB + b) * NCHUNK * QT_USH;
  const ushort_t* __restrict__ qhjH0 = qhj_hi + ((size_t)dir * HP * BB + b) * SS;
  const ushort_t* __restrict__ qhjL0 = qhj_lo + ((size_t)dir * HP * BB + b) * SS;

  if (t < HH) {
    float a, c;
    a = w1[t];   c = w1[HH + t];   wsq[t][0] = a*a; wsq[t][1] = c*c;
    a = w2[t];   c = w2[HH + t];   wsq[t][2] = a*a; wsq[t][3] = c*c;
    a = w3f_[t]; c = w3f_[HH + t]; wsq[t][4] = a*a; wsq[t][5] = c*c;
    a = w4f_[t]; c = w4f_[HH + t]; wsq[t][6] = a*a; wsq[t][7] = c*c;
    qlast_s[t] = q[(size_t)t * BB * SS + (size_t)b * SS + (SS - 1)];
  }

  // per-thread staging unit decode for qhj (unit e -> hp, s, part)
  // e in [0,896): hp = e>>3, s = (e&7)>>1, part = e&1
  // src = (part? qhj_lo : qhj_hi)[(dir*HP+hp)*BB*SS + b*SS + c*32 + s*8]
  // dst ushort off (within buf) = QT_USH + hp*QHJ_ROW + s*16 + part*8

  uint4 sT[5], sJ[4];
  // ---- prologue: stage chunk 0 ----
  {
    const uint4* gT = (const uint4*)(qTil + qt_base);
#pragma unroll
    for (int k = 0; k < 4; ++k) sT[k] = gT[t + k * 256];
    if (t < 64) sT[4] = gT[t + 1024];
#pragma unroll
    for (int k = 0; k < 4; ++k) {
      int e = t + k * 256;
      if (e < 896) {
        int hp = e >> 3, s = (e & 7) >> 1, part = e & 1;
        const ushort_t* src = (part ? qhjL0 : qhjH0) + (size_t)hp * BB * SS + s * 8;
        sJ[k] = *(const uint4*)src;
      }
    }
    uint4* dT = (uint4*)smem;
#pragma unroll
    for (int k = 0; k < 4; ++k) dT[t + k * 256] = sT[k];
    if (t < 64) dT[t + 1024] = sT[4];
#pragma unroll
    for (int k = 0; k < 4; ++k) {
      int e = t + k * 256;
      if (e < 896) {
        int hp = e >> 3, s = (e & 7) >> 1, part = e & 1;
        *(uint4*)(smem + QT_USH + hp * QHJ_ROW + s * 16 + part * 8) = sJ[k];
      }
    }
  }

  // ---- p fragments in registers: hi, lo, w2a^2*p (hi), w2b^2*p (hi) ----
  bf16x8 pHi[4], pLo[4], pGa[4], pGb[4];
#pragma unroll
  for (int kt = 0; kt < 4; ++kt) {
#pragma unroll
    for (int s = 0; s < 8; ++s) {
      int h = kt * 32 + 8 * lg + s;
      float pv = 0.f, ga = 0.f, gb = 0.f;
      if (h < HH) {
        pv = p[(size_t)h * BB * SS + (size_t)b * SS + rowbase + li];
        float wa = w2[h], wb = w2[HH + h];
        ga = pv * wa * wa;
        gb = pv * wb * wb;
      }
      ushort_t hi = f2bf(pv);
      pHi[kt][s] = (short)hi;
      pLo[kt][s] = (short)f2bf(pv - bf2f(hi));
      pGa[kt][s] = (short)f2bf(ga);
      pGb[kt][s] = (short)f2bf(gb);
    }
  }
  __syncthreads();   // buf0 ready

  f32x4 hmD[7];
#pragma unroll
  for (int nt = 0; nt < 7; ++nt) hmD[nt] = (f32x4){0.f, 0.f, 0.f, 0.f};
  float rowsum[4] = {0, 0, 0, 0};
  float amax[4] = {-INFINITY, -INFINITY, -INFINITY, -INFINITY};
  float m2a[4] = {-INFINITY, -INFINITY, -INFINITY, -INFINITY};
  float m2b[4] = {-INFINITY, -INFINITY, -INFINITY, -INFINITY};
  int aidx[4] = {0, 0, 0, 0};
  const float* nqa = nq2ws + ((size_t)(dir * 2 + 0) * BB + b) * SS;
  const float* nqb = nq2ws + ((size_t)(dir * 2 + 1) * BB + b) * SS;
  const float* nqp = nq2ws + ((size_t)(4 + dir) * BB + b) * SS;
  float* bw = bounce + w * (16 * BNC_PITCH);

  for (int c = 0; c < NCHUNK; ++c) {
    // ---- issue loads for chunk c+1 (regs; consumed after compute) ----
    if (c + 1 < NCHUNK) {
      const uint4* gT = (const uint4*)(qTil + qt_base + (size_t)(c + 1) * QT_USH);
#pragma unroll
      for (int k = 0; k < 4; ++k) sT[k] = gT[t + k * 256];
      if (t < 64) sT[4] = gT[t + 1024];
#pragma unroll
      for (int k = 0; k < 4; ++k) {
        int e = t + k * 256;
        if (e < 896) {
          int hp = e >> 3, s = (e & 7) >> 1, part = e & 1;
          const ushort_t* src = (part ? qhjL0 : qhjH0)
              + (size_t)hp * BB * SS + (c + 1) * 32 + s * 8;
          sJ[k] = *(const uint4*)src;
        }
      }
    }
    const ushort_t* bufc = smem + (c & 1) * BUF_USH;
    const ushort_t* qtH = bufc;
    const ushort_t* qtL = bufc + 32 * KP;
    const ushort_t* qjR = bufc + QT_USH;

    // ---- pass 1: two 16-j n-tiles ----
#pragma unroll
    for (int nn = 0; nn < 2; ++nn) {
      f32x4 attD = {0, 0, 0, 0}, gaD = {0, 0, 0, 0}, gbD = {0, 0, 0, 0};
#pragma unroll
      for (int kt = 0; kt < 4; ++kt) {
        const int bo = (nn * 16 + li) * KP + kt * 32 + 8 * lg;
        bf16x8 bHi = *(const bf16x8*)&qtH[bo];
        bf16x8 bLo = *(const bf16x8*)&qtL[bo];
        attD = __builtin_amdgcn_mfma_f32_16x16x32_bf16(pHi[kt], bHi, attD, 0, 0, 0);
        attD = __builtin_amdgcn_mfma_f32_16x16x32_bf16(pLo[kt], bHi, attD, 0, 0, 0);
        attD = __builtin_amdgcn_mfma_f32_16x16x32_bf16(pHi[kt], bLo, attD, 0, 0, 0);
        gaD  = __builtin_amdgcn_mfma_f32_16x16x32_bf16(pGa[kt], bHi, gaD, 0, 0, 0);
        gbD  = __builtin_amdgcn_mfma_f32_16x16x32_bf16(pGb[kt], bHi, gbD, 0, 0, 0);
      }
      const int j = c * 32 + nn * 16 + li;
      const float rp = nqp[j], ra = nqa[j], rb = nqb[j];
#pragma unroll
      for (int r = 0; r < 4; ++r) {
        float d = attD[r] * rp;
        rowsum[r] += d;
        if (d > amax[r]) { amax[r] = d; aidx[r] = j; }
        m2a[r] = fmaxf(m2a[r], gaD[r] * ra);
        m2b[r] = fmaxf(m2b[r], gbD[r] * rb);
        bw[(lg * 4 + r) * BNC_PITCH + nn * 16 + li] = d;
      }
    }
    // ---- wave-internal 16x32 transpose of d via bounce ----
    asm volatile("s_waitcnt lgkmcnt(0)" ::: "memory");
    __builtin_amdgcn_sched_barrier(0);
    float4 v0 = *(const float4*)&bw[li * BNC_PITCH + 8 * lg];
    float4 v1 = *(const float4*)&bw[li * BNC_PITCH + 8 * lg + 4];
    bf16x8 dHi, dLo;
    {
      float vv[8] = {v0.x, v0.y, v0.z, v0.w, v1.x, v1.y, v1.z, v1.w};
#pragma unroll
      for (int s = 0; s < 8; ++s) {
        ushort_t hi = f2bf(vv[s]);
        dHi[s] = (short)hi;
        dLo[s] = (short)f2bf(vv[s] - bf2f(hi));
      }
    }
    // ---- pass 2: hm accumulation from LDS-staged qhj ----
#pragma unroll
    for (int nt = 0; nt < 7; ++nt) {
      const int ro = (nt * 16 + li) * QHJ_ROW + lg * 16;
      bf16x8 qHi = *(const bf16x8*)&qjR[ro];
      bf16x8 qLo = *(const bf16x8*)&qjR[ro + 8];
      hmD[nt] = __builtin_amdgcn_mfma_f32_16x16x32_bf16(dHi, qHi, hmD[nt], 0, 0, 0);
      hmD[nt] = __builtin_amdgcn_mfma_f32_16x16x32_bf16(dLo, qHi, hmD[nt], 0, 0, 0);
      hmD[nt] = __builtin_amdgcn_mfma_f32_16x16x32_bf16(dHi, qLo, hmD[nt], 0, 0, 0);
    }
    // ---- write stage for c+1 (loads auto-waited via register deps) ----
    if (c + 1 < NCHUNK) {
      ushort_t* bufn = smem + ((c + 1) & 1) * BUF_USH;
      uint4* dT = (uint4*)bufn;
#pragma unroll
      for (int k = 0; k < 4; ++k) dT[t + k * 256] = sT[k];
      if (t < 64) dT[t + 1024] = sT[4];
#pragma unroll
      for (int k = 0; k < 4; ++k) {
        int e = t + k * 256;
        if (e < 896) {
          int hp = e >> 3, s = (e & 7) >> 1, part = e & 1;
          *(uint4*)(bufn + QT_USH + hp * QHJ_ROW + s * 16 + part * 8) = sJ[k];
        }
      }
    }
    __syncthreads();
  }

  // ---- stats reduce over li (rows are per-wave) ----
#pragma unroll
  for (int r = 0; r < 4; ++r) {
#pragma unroll
    for (int m = 1; m < 16; m <<= 1) {
      rowsum[r] += __shfl_xor(rowsum[r], m);
      float ov = __shfl_xor(amax[r], m);
      int   oi = __shfl_xor(aidx[r], m);
      if (ov > amax[r] || (ov == amax[r] && oi < aidx[r])) { amax[r] = ov; aidx[r] = oi; }
      m2a[r] = fmaxf(m2a[r], __shfl_xor(m2a[r], m));
      m2b[r] = fmaxf(m2b[r], __shfl_xor(m2b[r], m));
    }
  }
  if (li == 0) {
#pragma unroll
    for (int r = 0; r < 4; ++r) {
      const int row = lg * 4 + r;
      statb[w][row][0] = (rowsum[r] < 0.f) ? -1.f : 1.f;
      statb[w][row][1] = __int_as_float(aidx[r]);
      statb[w][row][2] = m2a[r];
      statb[w][row][3] = m2b[r];
    }
  }
  // hm to LDS (aliases chunk buffers; loop fully barriered out)
#pragma unroll
  for (int nt = 0; nt < 7; ++nt) {
#pragma unroll
    for (int r = 0; r < 4; ++r) {
      hmbuf[(size_t)(w * 16 + lg * 4 + r) * 116 + nt * 16 + li] = hmD[nt][r];
    }
  }
  __syncthreads();

  // ---- epilogue: 4 lanes per row, all 8 outputs ----
  {
    const int row = lane & 15, hq = lane >> 4;
    const int gi = rowbase + row;
    const float sg   = statb[w][row][0];
    const int   ax   = __float_as_int(statb[w][row][1]);
    const float m2av = statb[w][row][2], m2bv = statb[w][row][3];
    float ps0=0,ps1=0,ps2=0,ps3=0,ps4=0,ps5=0,ps6=0,ps7=0;
    float m1n0=0,m1n1=0,nq1a=0,nq1b=0;
    float m3n0=0,m3n1=0,nh0=0,nh1=0;
    float m4n0=0,m4n1=0,nq4a=0,nq4b=0;
#pragma unroll 5
    for (int k = 0; k < 25; ++k) {
      int h = k * 4 + hq;
      float pv = p[(size_t)h * BB * SS + (size_t)b * SS + gi];
      float hm = hmbuf[(size_t)(w * 16 + row) * 116 + h];
      float ql = qlast_s[h];
      float qi = q[(size_t)h * BB * SS + (size_t)b * SS + ax];
      float4 wv0 = *(const float4*)&wsq[h][0];
      float4 wv1 = *(const float4*)&wsq[h][4];
      float p2 = pv * pv;
      ps0 = fmaf(wv0.x, p2, ps0); ps1 = fmaf(wv0.y, p2, ps1);
      ps2 = fmaf(wv0.z, p2, ps2); ps3 = fmaf(wv0.w, p2, ps3);
      ps4 = fmaf(wv1.x, p2, ps4); ps5 = fmaf(wv1.y, p2, ps5);
      ps6 = fmaf(wv1.z, p2, ps6); ps7 = fmaf(wv1.w, p2, ps7);
      m1n0 = fmaf(wv0.x, pv * ql, m1n0); m1n1 = fmaf(wv0.y, pv * ql, m1n1);
      nq1a = fmaf(wv0.x, ql * ql, nq1a); nq1b = fmaf(wv0.y, ql * ql, nq1b);
      m3n0 = fmaf(wv1.x, pv * hm, m3n0); m3n1 = fmaf(wv1.y, pv * hm, m3n1);
      nh0  = fmaf(wv1.x, hm * hm, nh0);  nh1  = fmaf(wv1.y, hm * hm, nh1);
      m4n0 = fmaf(wv1.z, pv * qi, m4n0); m4n1 = fmaf(wv1.w, pv * qi, m4n1);
      nq4a = fmaf(wv1.z, qi * qi, nq4a); nq4b = fmaf(wv1.w, qi * qi, nq4b);
    }
#pragma unroll
    for (int m = 16; m < 64; m <<= 1) {
      ps0 += __shfl_xor(ps0, m);  ps1 += __shfl_xor(ps1, m);
      ps2 += __shfl_xor(ps2, m);  ps3 += __shfl_xor(ps3, m);
      ps4 += __shfl_xor(ps4, m);  ps5 += __shfl_xor(ps5, m);
      ps6 += __shfl_xor(ps6, m);  ps7 += __shfl_xor(ps7, m);
      m1n0 += __shfl_xor(m1n0, m); m1n1 += __shfl_xor(m1n1, m);
      nq1a += __shfl_xor(nq1a, m); nq1b += __shfl_xor(nq1b, m);
      m3n0 += __shfl_xor(m3n0, m); m3n1 += __shfl_xor(m3n1, m);
      nh0  += __shfl_xor(nh0,  m); nh1  += __shfl_xor(nh1,  m);
      m4n0 += __shfl_xor(m4n0, m); m4n1 += __shfl_xor(m4n1, m);
      nq4a += __shfl_xor(nq4a, m); nq4b += __shfl_xor(nq4b, m);
    }
    if (hq == 0) {
      const size_t base = (size_t)gi * (BB * 2) + (size_t)b * 2;
      out[(size_t)(0 + dir) * AS + base + 0] =
          m1n0 / (fmaxf(sqrtf(ps0), EPSF) * fmaxf(sqrtf(nq1a), EPSF));
      out[(size_t)(0 + dir) * AS + base + 1] =
          m1n1 / (fmaxf(sqrtf(ps1), EPSF) * fmaxf(sqrtf(nq1b), EPSF));
      out[(size_t)(2 + dir) * AS + base + 0] = m2av / fmaxf(sqrtf(ps2), EPSF);
      out[(size_t)(2 + dir) * AS + base + 1] = m2bv / fmaxf(sqrtf(ps3), EPSF);
      out[(size_t)(4 + dir) * AS + base + 0] =
          sg * m3n0 / (fmaxf(sqrtf(ps4), EPSF) * fmaxf(sqrtf(nh0), EPSF));
      out[(size_t)(4 + dir) * AS + base + 1] =
          sg * m3n1 / (fmaxf(sqrtf(ps5), EPSF) * fmaxf(sqrtf(nh1), EPSF));
      out[(size_t)(6 + dir) * AS + base + 0] =
          m4n0 / (fmaxf(sqrtf(ps6), EPSF) * fmaxf(sqrtf(nq4a), EPSF));
      out[(size_t)(6 + dir) * AS + base + 1] =
          m4n1 / (fmaxf(sqrtf(ps7), EPSF) * fmaxf(sqrtf(nq4b), EPSF));
    }
  }
}

extern "C" void kernel_launch(void* const* d_in, const int* in_sizes, int n_in,
                              void* d_out, int out_size, void* d_ws, size_t ws_size,
                              hipStream_t stream) {
  const float* pf  = (const float*)d_in[0];
  const float* pb  = (const float*)d_in[1];
  const float* qf  = (const float*)d_in[2];
  const float* qb  = (const float*)d_in[3];
  const float* w1f = (const float*)d_in[4];
  const float* w1b = (const float*)d_in[5];
  const float* w2f = (const float*)d_in[6];
  const float* w2b = (const float*)d_in[7];
  const float* w3f = (const float*)d_in[8];
  const float* w4f = (const float*)d_in[10];  // w3b/w4b unused by reference
  float* out = (float*)d_out;

  const size_t nq2_b  = (size_t)6 * BB * SS * 4;            //    589,824
  const size_t qhj_b  = (size_t)2 * HP * BB * SS * 2;       // 11,010,048 each
  float*    nq2    = (float*)d_ws;
  ushort_t* qhj_hi = (ushort_t*)((char*)d_ws + nq2_b);
  ushort_t* qhj_lo = (ushort_t*)((char*)d_ws + nq2_b + qhj_b);
  ushort_t* qTil   = (ushort_t*)((char*)d_ws + nq2_b + 2 * qhj_b);  // 26,738,688 B

  hipLaunchKernelGGL(qprep_kernel, dim3(2 * BB * 6), dim3(256), 0, stream,
                     qf, qb, w2f, w2b, nq2, qhj_hi, qhj_lo, qTil);
  hipLaunchKernelGGL(bimpm_fused, dim3(2 * BB * 6), dim3(256), 0, stream,
                     pf, pb, qf, qb, w1f, w1b, w2f, w2b, w3f, w4f,
                     nq2, qhj_hi, qhj_lo, qTil, out);
}

// Round 8
// 96.167 us; speedup vs baseline: 7.9621x; 1.6890x over previous
//
#include <hip/hip_runtime.h>
#include <math.h>

#define HH 100
#define HP 112
#define KP 136
#define BB 64
#define SS 384
#define EPSF 1e-6f
#define NCHUNK 12
#define QT_USH 8704            // 2 * 32 * KP ushorts (hi block | lo block) = 1088 slots
#define QHJ_USH 8192           // 1024 slots of 16B (112 rows x 72 ushorts + pad)
#define QHJ_ROW 72             // ushorts per row: 4 j-slots x (hi8+lo8) + 8 pad
#define BUF_USH (QT_USH + QHJ_USH)  // 16896 ushorts = 33792 B
#define BNC_PITCH 36

typedef __attribute__((ext_vector_type(8))) short bf16x8;
typedef __attribute__((ext_vector_type(4))) float f32x4;
typedef unsigned short ushort_t;

__device__ __forceinline__ ushort_t f2bf(float x) {
  unsigned u = __float_as_uint(x);
  unsigned r = (u + 0x7FFFu + ((u >> 16) & 1u)) >> 16;
  return (ushort_t)r;
}
__device__ __forceinline__ float bf2f(ushort_t h) {
  return __uint_as_float(((unsigned)h) << 16);
}
__device__ __forceinline__ void ld_g2l16(void* lds, const void* g) {
  __builtin_amdgcn_global_load_lds(
      (const __attribute__((address_space(1))) unsigned*)g,
      (__attribute__((address_space(3))) unsigned*)lds, 16, 0, 0);
}

// ---------------- Prep kernel: norms + qhj split + qT chunks, one pass ----------------
__global__ __launch_bounds__(256) void qprep_kernel(
    const float* __restrict__ qf, const float* __restrict__ qb,
    const float* __restrict__ w2f, const float* __restrict__ w2b,
    float* __restrict__ nq2, ushort_t* __restrict__ qhj_hi,
    ushort_t* __restrict__ qhj_lo, ushort_t* __restrict__ qTil)
{
  __shared__ __align__(16) float tile[HH * 68];
  __shared__ float w2sq_s[HH][2];
  const int blk = blockIdx.x;
  const int dir = blk / (BB * 6);
  const int rem = blk % (BB * 6);
  const int b   = rem / 6;
  const int jt  = rem % 6;
  const int j0  = jt * 64;
  const float* q  = dir ? qb : qf;
  const float* w2 = dir ? w2b : w2f;
  const int t = threadIdx.x;
  if (t < HH) {
    float a = w2[t], c = w2[HH + t];
    w2sq_s[t][0] = a * a; w2sq_s[t][1] = c * c;
  }
  for (int e = t; e < HH * 16; e += 256) {
    int h = e >> 4, j4 = e & 15;
    float4 v = *(const float4*)&q[((size_t)h * BB + b) * SS + j0 + j4 * 4];
    *(float4*)&tile[h * 68 + j4 * 4] = v;
  }
  __syncthreads();
  // qT chunk-interleaved: [dir][b][chunk][hi 32xKP | lo 32xKP]
  for (int e = t; e < 64 * KP; e += 256) {
    int jj = e / KP, kp = e % KP;
    float x = (kp < HH) ? tile[kp * 68 + jj] : 0.f;
    ushort_t hi = f2bf(x);
    int cg = jt * 2 + (jj >> 5);
    size_t base = ((size_t)(dir * BB + b) * NCHUNK + cg) * QT_USH
                + (size_t)(jj & 31) * KP + kp;
    qTil[base] = hi;
    qTil[base + 32 * KP] = f2bf(x - bf2f(hi));
  }
  // qhj hi/lo, zero-padded h in [100,112)
  for (int e = t; e < HP * 64; e += 256) {
    int hp = e >> 6, jj = e & 63;
    float x = (hp < HH) ? tile[hp * 68 + jj] : 0.f;
    ushort_t hi = f2bf(x);
    size_t o = ((size_t)(dir * HP + hp) * BB + b) * SS + j0 + jj;
    qhj_hi[o] = hi;
    qhj_lo[o] = f2bf(x - bf2f(hi));
  }
  // reciprocal norms
  if (t < 64) {
    float s0 = 0.f, s1 = 0.f, sp = 0.f;
    for (int h = 0; h < HH; ++h) {
      float v = tile[h * 68 + t];
      float v2 = v * v;
      s0 = fmaf(w2sq_s[h][0], v2, s0);
      s1 = fmaf(w2sq_s[h][1], v2, s1);
      sp += v2;
    }
    int j = j0 + t;
    nq2[((size_t)(dir * 2 + 0) * BB + b) * SS + j] = 1.0f / fmaxf(sqrtf(s0), EPSF);
    nq2[((size_t)(dir * 2 + 1) * BB + b) * SS + j] = 1.0f / fmaxf(sqrtf(s1), EPSF);
    nq2[((size_t)(4 + dir) * BB + b) * SS + j]     = 1.0f / fmaxf(sqrtf(sp), EPSF);
  }
}

// ---------------- Main fused kernel ----------------
__global__ __launch_bounds__(256) void bimpm_fused(
    const float* __restrict__ pf, const float* __restrict__ pb,
    const float* __restrict__ qf, const float* __restrict__ qb,
    const float* __restrict__ w1f, const float* __restrict__ w1b,
    const float* __restrict__ w2f, const float* __restrict__ w2b,
    const float* __restrict__ w3f_, const float* __restrict__ w4f_,
    const float* __restrict__ nq2ws,
    const ushort_t* __restrict__ qhj_hi, const ushort_t* __restrict__ qhj_lo,
    const ushort_t* __restrict__ qTil,
    float* __restrict__ out)
{
  // double-buffered chunk storage (qT + qhj); aliased by hmbuf after the loop
  __shared__ __align__(16) ushort_t smem[2 * BUF_USH];       // 67584 B
  __shared__ __align__(16) float bounce[4 * 16 * BNC_PITCH]; // 9216 B
  __shared__ __align__(16) float wsq[HH][8];                 // 3200 B
  __shared__ float qlast_s[HH];                              // 400 B
  __shared__ float statb[4][16][4];                          // 1024 B

  float* hmbuf = (float*)smem;   // [64][116] after main loop (29696 B < BUF)

  // XCD-aware work swizzle: 768 = 8 * 96, bijective
  const int bid  = blockIdx.x;
  const int work = (bid & 7) * 96 + (bid >> 3);
  const int dir = work / (BB * 6);
  const int rem = work % (BB * 6);
  const int b   = rem / 6;
  const int i0  = (rem % 6) * 64;

  const float* __restrict__ p  = dir ? pb : pf;
  const float* __restrict__ q  = dir ? qb : qf;
  const float* __restrict__ w1 = dir ? w1b : w1f;
  const float* __restrict__ w2 = dir ? w2b : w2f;
  const int t = threadIdx.x;
  const int w = t >> 6, lane = t & 63, li = lane & 15, lg = lane >> 4;
  const int rowbase = i0 + w * 16;
  const size_t AS = (size_t)SS * BB * 2;
  const size_t qt_base = (size_t)(dir * BB + b) * NCHUNK * QT_USH;
  const ushort_t* __restrict__ qhjH0 = qhj_hi + ((size_t)dir * HP * BB + b) * SS;
  const ushort_t* __restrict__ qhjL0 = qhj_lo + ((size_t)dir * HP * BB + b) * SS;

  if (t < HH) {
    float a, c;
    a = w1[t];   c = w1[HH + t];   wsq[t][0] = a*a; wsq[t][1] = c*c;
    a = w2[t];   c = w2[HH + t];   wsq[t][2] = a*a; wsq[t][3] = c*c;
    a = w3f_[t]; c = w3f_[HH + t]; wsq[t][4] = a*a; wsq[t][5] = c*c;
    a = w4f_[t]; c = w4f_[HH + t]; wsq[t][6] = a*a; wsq[t][7] = c*c;
    qlast_s[t] = q[(size_t)t * BB * SS + (size_t)b * SS + (SS - 1)];
  }

  // ---- async stage chunk cc into buffer bi (global_load_lds, no VGPR round-trip) ----
  auto stage_chunk = [&](int cc, int bi) {
    ushort_t* bufn = smem + bi * BUF_USH;
    // qT: 1088 linear 16B slots
    const char* gT = (const char*)(qTil + qt_base + (size_t)cc * QT_USH);
    char* lT = (char*)bufn;
#pragma unroll
    for (int k = 0; k < 4; ++k) {
      const int bslot = (k * 4 + w) * 64;                 // wave-uniform
      ld_g2l16(lT + bslot * 16, gT + (size_t)(bslot + lane) * 16);
    }
    if (w == 0) {
      ld_g2l16(lT + 1024 * 16, gT + (size_t)(1024 + lane) * 16);
    }
    // qhj: 1024 slots; slot u -> row hp=u/9, k=u%9 (k<8: s=k>>1,part=k&1; k==8: pad)
    char* lJ = (char*)(bufn + QT_USH);
#pragma unroll
    for (int k = 0; k < 4; ++k) {
      const int bslot = (k * 4 + w) * 64;                 // wave-uniform
      int u = bslot + lane;
      if (u > 1007) u = 1007;
      int hp = u / 9;
      int kk = u - hp * 9;
      int s    = (kk == 8) ? 0 : (kk >> 1);
      int part = (kk == 8) ? 0 : (kk & 1);
      const ushort_t* src = (part ? qhjL0 : qhjH0)
          + (size_t)hp * BB * SS + cc * 32 + s * 8;
      ld_g2l16(lJ + bslot * 16, src);
    }
  };

  stage_chunk(0, 0);

  // ---- p fragments in registers: hi, lo, w2a^2*p (hi), w2b^2*p (hi) ----
  bf16x8 pHi[4], pLo[4], pGa[4], pGb[4];
#pragma unroll
  for (int kt = 0; kt < 4; ++kt) {
#pragma unroll
    for (int s = 0; s < 8; ++s) {
      int h = kt * 32 + 8 * lg + s;
      float pv = 0.f, ga = 0.f, gb = 0.f;
      if (h < HH) {
        pv = p[(size_t)h * BB * SS + (size_t)b * SS + rowbase + li];
        float wa = w2[h], wb = w2[HH + h];
        ga = pv * wa * wa;
        gb = pv * wb * wb;
      }
      ushort_t hi = f2bf(pv);
      pHi[kt][s] = (short)hi;
      pLo[kt][s] = (short)f2bf(pv - bf2f(hi));
      pGa[kt][s] = (short)f2bf(ga);
      pGb[kt][s] = (short)f2bf(gb);
    }
  }
  __syncthreads();   // buf0 staged (vmcnt drained by barrier)

  f32x4 hmD[7];
#pragma unroll
  for (int nt = 0; nt < 7; ++nt) hmD[nt] = (f32x4){0.f, 0.f, 0.f, 0.f};
  float rowsum[4] = {0, 0, 0, 0};
  float amax[4] = {-INFINITY, -INFINITY, -INFINITY, -INFINITY};
  float m2a[4] = {-INFINITY, -INFINITY, -INFINITY, -INFINITY};
  float m2b[4] = {-INFINITY, -INFINITY, -INFINITY, -INFINITY};
  int aidx[4] = {0, 0, 0, 0};
  const float* nqa = nq2ws + ((size_t)(dir * 2 + 0) * BB + b) * SS;
  const float* nqb = nq2ws + ((size_t)(dir * 2 + 1) * BB + b) * SS;
  const float* nqp = nq2ws + ((size_t)(4 + dir) * BB + b) * SS;
  float* bw = bounce + w * (16 * BNC_PITCH);

  for (int c = 0; c < NCHUNK; ++c) {
    // issue async staging for c+1 into the other buffer (lands under compute)
    if (c + 1 < NCHUNK) stage_chunk(c + 1, (c + 1) & 1);

    const ushort_t* bufc = smem + (c & 1) * BUF_USH;
    const ushort_t* qtH = bufc;
    const ushort_t* qtL = bufc + 32 * KP;
    const ushort_t* qjR = bufc + QT_USH;

    // ---- pass 1: two 16-j n-tiles ----
#pragma unroll
    for (int nn = 0; nn < 2; ++nn) {
      f32x4 attD = {0, 0, 0, 0}, gaD = {0, 0, 0, 0}, gbD = {0, 0, 0, 0};
#pragma unroll
      for (int kt = 0; kt < 4; ++kt) {
        const int bo = (nn * 16 + li) * KP + kt * 32 + 8 * lg;
        bf16x8 bHi = *(const bf16x8*)&qtH[bo];
        bf16x8 bLo = *(const bf16x8*)&qtL[bo];
        attD = __builtin_amdgcn_mfma_f32_16x16x32_bf16(pHi[kt], bHi, attD, 0, 0, 0);
        attD = __builtin_amdgcn_mfma_f32_16x16x32_bf16(pLo[kt], bHi, attD, 0, 0, 0);
        attD = __builtin_amdgcn_mfma_f32_16x16x32_bf16(pHi[kt], bLo, attD, 0, 0, 0);
        gaD  = __builtin_amdgcn_mfma_f32_16x16x32_bf16(pGa[kt], bHi, gaD, 0, 0, 0);
        gbD  = __builtin_amdgcn_mfma_f32_16x16x32_bf16(pGb[kt], bHi, gbD, 0, 0, 0);
      }
      const int j = c * 32 + nn * 16 + li;
      const float rp = nqp[j], ra = nqa[j], rb = nqb[j];
#pragma unroll
      for (int r = 0; r < 4; ++r) {
        float d = attD[r] * rp;
        rowsum[r] += d;
        if (d > amax[r]) { amax[r] = d; aidx[r] = j; }
        m2a[r] = fmaxf(m2a[r], gaD[r] * ra);
        m2b[r] = fmaxf(m2b[r], gbD[r] * rb);
        bw[(lg * 4 + r) * BNC_PITCH + nn * 16 + li] = d;
      }
    }
    // ---- wave-internal 16x32 transpose of d via bounce ----
    asm volatile("s_waitcnt lgkmcnt(0)" ::: "memory");
    __builtin_amdgcn_sched_barrier(0);
    float4 v0 = *(const float4*)&bw[li * BNC_PITCH + 8 * lg];
    float4 v1 = *(const float4*)&bw[li * BNC_PITCH + 8 * lg + 4];
    bf16x8 dHi, dLo;
    {
      float vv[8] = {v0.x, v0.y, v0.z, v0.w, v1.x, v1.y, v1.z, v1.w};
#pragma unroll
      for (int s = 0; s < 8; ++s) {
        ushort_t hi = f2bf(vv[s]);
        dHi[s] = (short)hi;
        dLo[s] = (short)f2bf(vv[s] - bf2f(hi));
      }
    }
    // ---- pass 2: hm accumulation from LDS-staged qhj ----
#pragma unroll
    for (int nt = 0; nt < 7; ++nt) {
      const int ro = (nt * 16 + li) * QHJ_ROW + lg * 16;
      bf16x8 qHi = *(const bf16x8*)&qjR[ro];
      bf16x8 qLo = *(const bf16x8*)&qjR[ro + 8];
      hmD[nt] = __builtin_amdgcn_mfma_f32_16x16x32_bf16(dHi, qHi, hmD[nt], 0, 0, 0);
      hmD[nt] = __builtin_amdgcn_mfma_f32_16x16x32_bf16(dLo, qHi, hmD[nt], 0, 0, 0);
      hmD[nt] = __builtin_amdgcn_mfma_f32_16x16x32_bf16(dHi, qLo, hmD[nt], 0, 0, 0);
    }
    __syncthreads();   // drains vmcnt (c+1 staged) + all reads of buf c done
  }

  // ---- stats reduce over li (rows are per-wave) ----
#pragma unroll
  for (int r = 0; r < 4; ++r) {
#pragma unroll
    for (int m = 1; m < 16; m <<= 1) {
      rowsum[r] += __shfl_xor(rowsum[r], m);
      float ov = __shfl_xor(amax[r], m);
      int   oi = __shfl_xor(aidx[r], m);
      if (ov > amax[r] || (ov == amax[r] && oi < aidx[r])) { amax[r] = ov; aidx[r] = oi; }
      m2a[r] = fmaxf(m2a[r], __shfl_xor(m2a[r], m));
      m2b[r] = fmaxf(m2b[r], __shfl_xor(m2b[r], m));
    }
  }
  if (li == 0) {
#pragma unroll
    for (int r = 0; r < 4; ++r) {
      const int row = lg * 4 + r;
      statb[w][row][0] = (rowsum[r] < 0.f) ? -1.f : 1.f;
      statb[w][row][1] = __int_as_float(aidx[r]);
      statb[w][row][2] = m2a[r];
      statb[w][row][3] = m2b[r];
    }
  }
  // hm to LDS (aliases chunk buffers; loop fully barriered out)
#pragma unroll
  for (int nt = 0; nt < 7; ++nt) {
#pragma unroll
    for (int r = 0; r < 4; ++r) {
      hmbuf[(size_t)(w * 16 + lg * 4 + r) * 116 + nt * 16 + li] = hmD[nt][r];
    }
  }
  __syncthreads();

  // ---- epilogue: 4 lanes per row, all 8 outputs ----
  {
    const int row = lane & 15, hq = lane >> 4;
    const int gi = rowbase + row;
    const float sg   = statb[w][row][0];
    const int   ax   = __float_as_int(statb[w][row][1]);
    const float m2av = statb[w][row][2], m2bv = statb[w][row][3];
    float ps0=0,ps1=0,ps2=0,ps3=0,ps4=0,ps5=0,ps6=0,ps7=0;
    float m1n0=0,m1n1=0,nq1a=0,nq1b=0;
    float m3n0=0,m3n1=0,nh0=0,nh1=0;
    float m4n0=0,m4n1=0,nq4a=0,nq4b=0;
#pragma unroll 5
    for (int k = 0; k < 25; ++k) {
      int h = k * 4 + hq;
      float pv = p[(size_t)h * BB * SS + (size_t)b * SS + gi];
      float hm = hmbuf[(size_t)(w * 16 + row) * 116 + h];
      float ql = qlast_s[h];
      float qi = q[(size_t)h * BB * SS + (size_t)b * SS + ax];
      float4 wv0 = *(const float4*)&wsq[h][0];
      float4 wv1 = *(const float4*)&wsq[h][4];
      float p2 = pv * pv;
      ps0 = fmaf(wv0.x, p2, ps0); ps1 = fmaf(wv0.y, p2, ps1);
      ps2 = fmaf(wv0.z, p2, ps2); ps3 = fmaf(wv0.w, p2, ps3);
      ps4 = fmaf(wv1.x, p2, ps4); ps5 = fmaf(wv1.y, p2, ps5);
      ps6 = fmaf(wv1.z, p2, ps6); ps7 = fmaf(wv1.w, p2, ps7);
      m1n0 = fmaf(wv0.x, pv * ql, m1n0); m1n1 = fmaf(wv0.y, pv * ql, m1n1);
      nq1a = fmaf(wv0.x, ql * ql, nq1a); nq1b = fmaf(wv0.y, ql * ql, nq1b);
      m3n0 = fmaf(wv1.x, pv * hm, m3n0); m3n1 = fmaf(wv1.y, pv * hm, m3n1);
      nh0  = fmaf(wv1.x, hm * hm, nh0);  nh1  = fmaf(wv1.y, hm * hm, nh1);
      m4n0 = fmaf(wv1.z, pv * qi, m4n0); m4n1 = fmaf(wv1.w, pv * qi, m4n1);
      nq4a = fmaf(wv1.z, qi * qi, nq4a); nq4b = fmaf(wv1.w, qi * qi, nq4b);
    }
#pragma unroll
    for (int m = 16; m < 64; m <<= 1) {
      ps0 += __shfl_xor(ps0, m);  ps1 += __shfl_xor(ps1, m);
      ps2 += __shfl_xor(ps2, m);  ps3 += __shfl_xor(ps3, m);
      ps4 += __shfl_xor(ps4, m);  ps5 += __shfl_xor(ps5, m);
      ps6 += __shfl_xor(ps6, m);  ps7 += __shfl_xor(ps7, m);
      m1n0 += __shfl_xor(m1n0, m); m1n1 += __shfl_xor(m1n1, m);
      nq1a += __shfl_xor(nq1a, m); nq1b += __shfl_xor(nq1b, m);
      m3n0 += __shfl_xor(m3n0, m); m3n1 += __shfl_xor(m3n1, m);
      nh0  += __shfl_xor(nh0,  m); nh1  += __shfl_xor(nh1,  m);
      m4n0 += __shfl_xor(m4n0, m); m4n1 += __shfl_xor(m4n1, m);
      nq4a += __shfl_xor(nq4a, m); nq4b += __shfl_xor(nq4b, m);
    }
    if (hq == 0) {
      const size_t base = (size_t)gi * (BB * 2) + (size_t)b * 2;
      out[(size_t)(0 + dir) * AS + base + 0] =
          m1n0 / (fmaxf(sqrtf(ps0), EPSF) * fmaxf(sqrtf(nq1a), EPSF));
      out[(size_t)(0 + dir) * AS + base + 1] =
          m1n1 / (fmaxf(sqrtf(ps1), EPSF) * fmaxf(sqrtf(nq1b), EPSF));
      out[(size_t)(2 + dir) * AS + base + 0] = m2av / fmaxf(sqrtf(ps2), EPSF);
      out[(size_t)(2 + dir) * AS + base + 1] = m2bv / fmaxf(sqrtf(ps3), EPSF);
      out[(size_t)(4 + dir) * AS + base + 0] =
          sg * m3n0 / (fmaxf(sqrtf(ps4), EPSF) * fmaxf(sqrtf(nh0), EPSF));
      out[(size_t)(4 + dir) * AS + base + 1] =
          sg * m3n1 / (fmaxf(sqrtf(ps5), EPSF) * fmaxf(sqrtf(nh1), EPSF));
      out[(size_t)(6 + dir) * AS + base + 0] =
          m4n0 / (fmaxf(sqrtf(ps6), EPSF) * fmaxf(sqrtf(nq4a), EPSF));
      out[(size_t)(6 + dir) * AS + base + 1] =
          m4n1 / (fmaxf(sqrtf(ps7), EPSF) * fmaxf(sqrtf(nq4b), EPSF));
    }
  }
}

extern "C" void kernel_launch(void* const* d_in, const int* in_sizes, int n_in,
                              void* d_out, int out_size, void* d_ws, size_t ws_size,
                              hipStream_t stream) {
  const float* pf  = (const float*)d_in[0];
  const float* pb  = (const float*)d_in[1];
  const float* qf  = (const float*)d_in[2];
  const float* qb  = (const float*)d_in[3];
  const float* w1f = (const float*)d_in[4];
  const float* w1b = (const float*)d_in[5];
  const float* w2f = (const float*)d_in[6];
  const float* w2b = (const float*)d_in[7];
  const float* w3f = (const float*)d_in[8];
  const float* w4f = (const float*)d_in[10];  // w3b/w4b unused by reference
  float* out = (float*)d_out;

  const size_t nq2_b  = (size_t)6 * BB * SS * 4;            //    589,824
  const size_t qhj_b  = (size_t)2 * HP * BB * SS * 2;       // 11,010,048 each
  float*    nq2    = (float*)d_ws;
  ushort_t* qhj_hi = (ushort_t*)((char*)d_ws + nq2_b);
  ushort_t* qhj_lo = (ushort_t*)((char*)d_ws + nq2_b + qhj_b);
  ushort_t* qTil   = (ushort_t*)((char*)d_ws + nq2_b + 2 * qhj_b);  // 26,738,688 B

  hipLaunchKernelGGL(qprep_kernel, dim3(2 * BB * 6), dim3(256), 0, stream,
                     qf, qb, w2f, w2b, nq2, qhj_hi, qhj_lo, qTil);
  hipLaunchKernelGGL(bimpm_fused, dim3(2 * BB * 6), dim3(256), 0, stream,
                     pf, pb, qf, qb, w1f, w1b, w2f, w2b, w3f, w4f,
                     nq2, qhj_hi, qhj_lo, qTil, out);
}

// Round 9
// 95.247 us; speedup vs baseline: 8.0390x; 1.0097x over previous
//
#include <hip/hip_runtime.h>
#include <math.h>

#define HH 100
#define HP 112
#define KP 136
#define BB 64
#define SS 384
#define EPSF 1e-6f
#define NCH 24                  // 16-j chunks
#define QT16 4352               // ush per chunk: hi 16*KP + lo 16*KP
#define QHJ16 4480              // ush per chunk: 112 rows * 40
#define BUFU (QT16 + QHJ16)     // 8832 ush = 17664 B
#define NSLOT 1104              // 16B slots per chunk buffer
#define BNCP 20                 // bounce pitch (floats)

typedef __attribute__((ext_vector_type(8))) short bf16x8;
typedef __attribute__((ext_vector_type(4))) float f32x4;
typedef unsigned short ushort_t;

__device__ __forceinline__ ushort_t f2bf(float x) {
  unsigned u = __float_as_uint(x);
  unsigned r = (u + 0x7FFFu + ((u >> 16) & 1u)) >> 16;
  return (ushort_t)r;
}
__device__ __forceinline__ float bf2f(ushort_t h) {
  return __uint_as_float(((unsigned)h) << 16);
}
__device__ __forceinline__ void ld_g2l16(void* lds, const void* g) {
  __builtin_amdgcn_global_load_lds(
      (const __attribute__((address_space(1))) unsigned*)g,
      (__attribute__((address_space(3))) unsigned*)lds, 16, 0, 0);
}

// ---------------- Prep kernel: norms + qhj split + 16j qT chunks ----------------
__global__ __launch_bounds__(256) void qprep_kernel(
    const float* __restrict__ qf, const float* __restrict__ qb,
    const float* __restrict__ w2f, const float* __restrict__ w2b,
    float* __restrict__ nq2, ushort_t* __restrict__ qhj_hi,
    ushort_t* __restrict__ qhj_lo, ushort_t* __restrict__ qTil)
{
  __shared__ __align__(16) float tile[HH * 68];
  __shared__ float w2sq_s[HH][2];
  const int blk = blockIdx.x;
  const int dir = blk / (BB * 6);
  const int rem = blk % (BB * 6);
  const int b   = rem / 6;
  const int jt  = rem % 6;
  const int j0  = jt * 64;
  const float* q  = dir ? qb : qf;
  const float* w2 = dir ? w2b : w2f;
  const int t = threadIdx.x;
  if (t < HH) {
    float a = w2[t], c = w2[HH + t];
    w2sq_s[t][0] = a * a; w2sq_s[t][1] = c * c;
  }
  for (int e = t; e < HH * 16; e += 256) {
    int h = e >> 4, j4 = e & 15;
    float4 v = *(const float4*)&q[((size_t)h * BB + b) * SS + j0 + j4 * 4];
    *(float4*)&tile[h * 68 + j4 * 4] = v;
  }
  __syncthreads();
  // qT 16j-chunk-interleaved: [dir][b][chunk16][hi 16xKP | lo 16xKP]
  for (int e = t; e < 64 * KP; e += 256) {
    int jj = e / KP, kp = e % KP;
    float x = (kp < HH) ? tile[kp * 68 + jj] : 0.f;
    ushort_t hi = f2bf(x);
    int cg = jt * 4 + (jj >> 4);
    size_t base = ((size_t)(dir * BB + b) * NCH + cg) * QT16
                + (size_t)(jj & 15) * KP + kp;
    qTil[base] = hi;
    qTil[base + 16 * KP] = f2bf(x - bf2f(hi));
  }
  // qhj hi/lo, zero-padded h in [100,112)
  for (int e = t; e < HP * 64; e += 256) {
    int hp = e >> 6, jj = e & 63;
    float x = (hp < HH) ? tile[hp * 68 + jj] : 0.f;
    ushort_t hi = f2bf(x);
    size_t o = ((size_t)(dir * HP + hp) * BB + b) * SS + j0 + jj;
    qhj_hi[o] = hi;
    qhj_lo[o] = f2bf(x - bf2f(hi));
  }
  // reciprocal norms
  if (t < 64) {
    float s0 = 0.f, s1 = 0.f, sp = 0.f;
    for (int h = 0; h < HH; ++h) {
      float v = tile[h * 68 + t];
      float v2 = v * v;
      s0 = fmaf(w2sq_s[h][0], v2, s0);
      s1 = fmaf(w2sq_s[h][1], v2, s1);
      sp += v2;
    }
    int j = j0 + t;
    nq2[((size_t)(dir * 2 + 0) * BB + b) * SS + j] = 1.0f / fmaxf(sqrtf(s0), EPSF);
    nq2[((size_t)(dir * 2 + 1) * BB + b) * SS + j] = 1.0f / fmaxf(sqrtf(s1), EPSF);
    nq2[((size_t)(4 + dir) * BB + b) * SS + j]     = 1.0f / fmaxf(sqrtf(sp), EPSF);
  }
}

// ---------------- Main fused kernel: 3 blocks/CU, 16-j chunks ----------------
__global__ __launch_bounds__(256, 3) void bimpm_fused(
    const float* __restrict__ pf, const float* __restrict__ pb,
    const float* __restrict__ qf, const float* __restrict__ qb,
    const float* __restrict__ w1f, const float* __restrict__ w1b,
    const float* __restrict__ w2f, const float* __restrict__ w2b,
    const float* __restrict__ w3f_, const float* __restrict__ w4f_,
    const float* __restrict__ nq2ws,
    const ushort_t* __restrict__ qhj_hi, const ushort_t* __restrict__ qhj_lo,
    const ushort_t* __restrict__ qTil,
    float* __restrict__ out)
{
  __shared__ __align__(16) ushort_t smem[2 * BUFU];          // 35328 B
  __shared__ __align__(16) float bounce[4 * 16 * BNCP];      // 5120 B
  __shared__ __align__(16) float wsq[HH][8];                 // 3200 B
  __shared__ float qlast_s[HH];                              // 400 B
  __shared__ float statb[4][16][4];                          // 1024 B

  float* hmbuf = (float*)smem;   // [64][116] after main loop (29696 B < 35328)

  // XCD-aware work swizzle: 768 = 8 * 96, bijective
  const int bid  = blockIdx.x;
  const int work = (bid & 7) * 96 + (bid >> 3);
  const int dir = work / (BB * 6);
  const int rem = work % (BB * 6);
  const int b   = rem / 6;
  const int i0  = (rem % 6) * 64;

  const float* __restrict__ p  = dir ? pb : pf;
  const float* __restrict__ q  = dir ? qb : qf;
  const float* __restrict__ w1 = dir ? w1b : w1f;
  const float* __restrict__ w2 = dir ? w2b : w2f;
  const int t = threadIdx.x;
  const int w = t >> 6, lane = t & 63, li = lane & 15, lg = lane >> 4;
  const int rowbase = i0 + w * 16;
  const size_t AS = (size_t)SS * BB * 2;
  const size_t qt_base = (size_t)(dir * BB + b) * NCH * QT16;
  const ushort_t* __restrict__ qhjH0 = qhj_hi + ((size_t)dir * HP * BB + b) * SS;
  const ushort_t* __restrict__ qhjL0 = qhj_lo + ((size_t)dir * HP * BB + b) * SS;

  if (t < HH) {
    float a, c;
    a = w1[t];   c = w1[HH + t];   wsq[t][0] = a*a; wsq[t][1] = c*c;
    a = w2[t];   c = w2[HH + t];   wsq[t][2] = a*a; wsq[t][3] = c*c;
    a = w3f_[t]; c = w3f_[HH + t]; wsq[t][4] = a*a; wsq[t][5] = c*c;
    a = w4f_[t]; c = w4f_[HH + t]; wsq[t][6] = a*a; wsq[t][7] = c*c;
    qlast_s[t] = q[(size_t)t * BB * SS + (size_t)b * SS + (SS - 1)];
  }

  // ---- async stage chunk cc into buffer bi (contiguous 1104-slot stream) ----
  auto stage_chunk = [&](int cc, int bi) {
    char* bufn = (char*)(smem + bi * BUFU);
    const char* gT = (const char*)(qTil + qt_base + (size_t)cc * QT16);
#pragma unroll
    for (int k = 0; k < 5; ++k) {
      const int u = k * 256 + t;
      if (k < 4 || t < (NSLOT - 1024)) {
        int v = (u < 544) ? 0 : (u - 544);
        int hp = v / 5;
        int kk = v - hp * 5;
        int part = kk & 1, s = kk >> 1;
        if (kk == 4) { part = 0; s = 0; }     // pad slot: benign duplicate
        const char* srcJ = (const char*)((part ? qhjL0 : qhjH0)
                            + (size_t)hp * BB * SS + cc * 16 + s * 8);
        const char* srcT = gT + (size_t)u * 16;
        const char* src = (u < 544) ? srcT : srcJ;
        ld_g2l16(bufn + (size_t)(k * 256 + w * 64) * 16, src);
      }
    }
  };

  stage_chunk(0, 0);

  // ---- p fragments in registers: hi, lo, w2a^2*p (hi), w2b^2*p (hi) ----
  bf16x8 pHi[4], pLo[4], pGa[4], pGb[4];
#pragma unroll
  for (int kt = 0; kt < 4; ++kt) {
#pragma unroll
    for (int s = 0; s < 8; ++s) {
      int h = kt * 32 + 8 * lg + s;
      float pv = 0.f, ga = 0.f, gb = 0.f;
      if (h < HH) {
        pv = p[(size_t)h * BB * SS + (size_t)b * SS + rowbase + li];
        float wa = w2[h], wb = w2[HH + h];
        ga = pv * wa * wa;
        gb = pv * wb * wb;
      }
      ushort_t hi = f2bf(pv);
      pHi[kt][s] = (short)hi;
      pLo[kt][s] = (short)f2bf(pv - bf2f(hi));
      pGa[kt][s] = (short)f2bf(ga);
      pGb[kt][s] = (short)f2bf(gb);
    }
  }
  __syncthreads();   // buf0 staged (vmcnt drained by barrier)

  f32x4 hmD[7];
#pragma unroll
  for (int nt = 0; nt < 7; ++nt) hmD[nt] = (f32x4){0.f, 0.f, 0.f, 0.f};
  float rowsum[4] = {0, 0, 0, 0};
  float amax[4] = {-INFINITY, -INFINITY, -INFINITY, -INFINITY};
  float m2a[4] = {-INFINITY, -INFINITY, -INFINITY, -INFINITY};
  float m2b[4] = {-INFINITY, -INFINITY, -INFINITY, -INFINITY};
  int aidx[4] = {0, 0, 0, 0};
  const float* nqa = nq2ws + ((size_t)(dir * 2 + 0) * BB + b) * SS;
  const float* nqb = nq2ws + ((size_t)(dir * 2 + 1) * BB + b) * SS;
  const float* nqp = nq2ws + ((size_t)(4 + dir) * BB + b) * SS;
  float* bw = bounce + w * (16 * BNCP);

  for (int c = 0; c < NCH; ++c) {
    if (c + 1 < NCH) stage_chunk(c + 1, (c + 1) & 1);

    const ushort_t* bufc = smem + (c & 1) * BUFU;
    const ushort_t* qtH = bufc;
    const ushort_t* qtL = bufc + 16 * KP;
    const ushort_t* qjR = bufc + QT16;

    // ---- pass 1: one 16-j n-tile ----
    f32x4 attD = {0, 0, 0, 0}, gaD = {0, 0, 0, 0}, gbD = {0, 0, 0, 0};
#pragma unroll
    for (int kt = 0; kt < 4; ++kt) {
      const int bo = li * KP + kt * 32 + 8 * lg;
      bf16x8 bHi = *(const bf16x8*)&qtH[bo];
      bf16x8 bLo = *(const bf16x8*)&qtL[bo];
      attD = __builtin_amdgcn_mfma_f32_16x16x32_bf16(pHi[kt], bHi, attD, 0, 0, 0);
      attD = __builtin_amdgcn_mfma_f32_16x16x32_bf16(pLo[kt], bHi, attD, 0, 0, 0);
      attD = __builtin_amdgcn_mfma_f32_16x16x32_bf16(pHi[kt], bLo, attD, 0, 0, 0);
      gaD  = __builtin_amdgcn_mfma_f32_16x16x32_bf16(pGa[kt], bHi, gaD, 0, 0, 0);
      gbD  = __builtin_amdgcn_mfma_f32_16x16x32_bf16(pGb[kt], bHi, gbD, 0, 0, 0);
    }
    {
      const int j = c * 16 + li;
      const float rp = nqp[j], ra = nqa[j], rb = nqb[j];
#pragma unroll
      for (int r = 0; r < 4; ++r) {
        float d = attD[r] * rp;
        rowsum[r] += d;
        if (d > amax[r]) { amax[r] = d; aidx[r] = j; }
        m2a[r] = fmaxf(m2a[r], gaD[r] * ra);
        m2b[r] = fmaxf(m2b[r], gbD[r] * rb);
        bw[(lg * 4 + r) * BNCP + li] = d;
      }
    }
    // ---- wave-internal 16x16 transpose of d via bounce ----
    asm volatile("s_waitcnt lgkmcnt(0)" ::: "memory");
    __builtin_amdgcn_sched_barrier(0);
    bf16x8 dHi = {0,0,0,0,0,0,0,0}, dLo = {0,0,0,0,0,0,0,0};
    if (lg < 2) {
      float4 v0 = *(const float4*)&bw[li * BNCP + lg * 8];
      float4 v1 = *(const float4*)&bw[li * BNCP + lg * 8 + 4];
      float vv[8] = {v0.x, v0.y, v0.z, v0.w, v1.x, v1.y, v1.z, v1.w};
#pragma unroll
      for (int s = 0; s < 8; ++s) {
        ushort_t hi = f2bf(vv[s]);
        dHi[s] = (short)hi;
        dLo[s] = (short)f2bf(vv[s] - bf2f(hi));
      }
    }
    // ---- pass 2: hm accumulation (A upper K-half is exact zero) ----
#pragma unroll
    for (int nt = 0; nt < 7; ++nt) {
      const int ro = (nt * 16 + li) * 40 + (lg & 1) * 16;
      bf16x8 qHi = *(const bf16x8*)&qjR[ro];
      bf16x8 qLo = *(const bf16x8*)&qjR[ro + 8];
      hmD[nt] = __builtin_amdgcn_mfma_f32_16x16x32_bf16(dHi, qHi, hmD[nt], 0, 0, 0);
      hmD[nt] = __builtin_amdgcn_mfma_f32_16x16x32_bf16(dLo, qHi, hmD[nt], 0, 0, 0);
      hmD[nt] = __builtin_amdgcn_mfma_f32_16x16x32_bf16(dHi, qLo, hmD[nt], 0, 0, 0);
    }
    __syncthreads();   // drains vmcnt (c+1 staged) + all reads of buf c done
  }

  // ---- stats reduce over li (rows are per-wave) ----
#pragma unroll
  for (int r = 0; r < 4; ++r) {
#pragma unroll
    for (int m = 1; m < 16; m <<= 1) {
      rowsum[r] += __shfl_xor(rowsum[r], m);
      float ov = __shfl_xor(amax[r], m);
      int   oi = __shfl_xor(aidx[r], m);
      if (ov > amax[r] || (ov == amax[r] && oi < aidx[r])) { amax[r] = ov; aidx[r] = oi; }
      m2a[r] = fmaxf(m2a[r], __shfl_xor(m2a[r], m));
      m2b[r] = fmaxf(m2b[r], __shfl_xor(m2b[r], m));
    }
  }
  if (li == 0) {
#pragma unroll
    for (int r = 0; r < 4; ++r) {
      const int row = lg * 4 + r;
      statb[w][row][0] = (rowsum[r] < 0.f) ? -1.f : 1.f;
      statb[w][row][1] = __int_as_float(aidx[r]);
      statb[w][row][2] = m2a[r];
      statb[w][row][3] = m2b[r];
    }
  }
  // hm to LDS (aliases chunk buffers; loop fully barriered out)
#pragma unroll
  for (int nt = 0; nt < 7; ++nt) {
#pragma unroll
    for (int r = 0; r < 4; ++r) {
      hmbuf[(size_t)(w * 16 + lg * 4 + r) * 116 + nt * 16 + li] = hmD[nt][r];
    }
  }
  __syncthreads();

  // ---- epilogue: 4 lanes per row, all 8 outputs ----
  {
    const int row = lane & 15, hq = lane >> 4;
    const int gi = rowbase + row;
    const float sg   = statb[w][row][0];
    const int   ax   = __float_as_int(statb[w][row][1]);
    const float m2av = statb[w][row][2], m2bv = statb[w][row][3];
    float ps0=0,ps1=0,ps2=0,ps3=0,ps4=0,ps5=0,ps6=0,ps7=0;
    float m1n0=0,m1n1=0,nq1a=0,nq1b=0;
    float m3n0=0,m3n1=0,nh0=0,nh1=0;
    float m4n0=0,m4n1=0,nq4a=0,nq4b=0;
#pragma unroll 5
    for (int k = 0; k < 25; ++k) {
      int h = k * 4 + hq;
      float pv = p[(size_t)h * BB * SS + (size_t)b * SS + gi];
      float hm = hmbuf[(size_t)(w * 16 + row) * 116 + h];
      float ql = qlast_s[h];
      float qi = q[(size_t)h * BB * SS + (size_t)b * SS + ax];
      float4 wv0 = *(const float4*)&wsq[h][0];
      float4 wv1 = *(const float4*)&wsq[h][4];
      float p2 = pv * pv;
      ps0 = fmaf(wv0.x, p2, ps0); ps1 = fmaf(wv0.y, p2, ps1);
      ps2 = fmaf(wv0.z, p2, ps2); ps3 = fmaf(wv0.w, p2, ps3);
      ps4 = fmaf(wv1.x, p2, ps4); ps5 = fmaf(wv1.y, p2, ps5);
      ps6 = fmaf(wv1.z, p2, ps6); ps7 = fmaf(wv1.w, p2, ps7);
      m1n0 = fmaf(wv0.x, pv * ql, m1n0); m1n1 = fmaf(wv0.y, pv * ql, m1n1);
      nq1a = fmaf(wv0.x, ql * ql, nq1a); nq1b = fmaf(wv0.y, ql * ql, nq1b);
      m3n0 = fmaf(wv1.x, pv * hm, m3n0); m3n1 = fmaf(wv1.y, pv * hm, m3n1);
      nh0  = fmaf(wv1.x, hm * hm, nh0);  nh1  = fmaf(wv1.y, hm * hm, nh1);
      m4n0 = fmaf(wv1.z, pv * qi, m4n0); m4n1 = fmaf(wv1.w, pv * qi, m4n1);
      nq4a = fmaf(wv1.z, qi * qi, nq4a); nq4b = fmaf(wv1.w, qi * qi, nq4b);
    }
#pragma unroll
    for (int m = 16; m < 64; m <<= 1) {
      ps0 += __shfl_xor(ps0, m);  ps1 += __shfl_xor(ps1, m);
      ps2 += __shfl_xor(ps2, m);  ps3 += __shfl_xor(ps3, m);
      ps4 += __shfl_xor(ps4, m);  ps5 += __shfl_xor(ps5, m);
      ps6 += __shfl_xor(ps6, m);  ps7 += __shfl_xor(ps7, m);
      m1n0 += __shfl_xor(m1n0, m); m1n1 += __shfl_xor(m1n1, m);
      nq1a += __shfl_xor(nq1a, m); nq1b += __shfl_xor(nq1b, m);
      m3n0 += __shfl_xor(m3n0, m); m3n1 += __shfl_xor(m3n1, m);
      nh0  += __shfl_xor(nh0,  m); nh1  += __shfl_xor(nh1,  m);
      m4n0 += __shfl_xor(m4n0, m); m4n1 += __shfl_xor(m4n1, m);
      nq4a += __shfl_xor(nq4a, m); nq4b += __shfl_xor(nq4b, m);
    }
    if (hq == 0) {
      const size_t base = (size_t)gi * (BB * 2) + (size_t)b * 2;
      out[(size_t)(0 + dir) * AS + base + 0] =
          m1n0 / (fmaxf(sqrtf(ps0), EPSF) * fmaxf(sqrtf(nq1a), EPSF));
      out[(size_t)(0 + dir) * AS + base + 1] =
          m1n1 / (fmaxf(sqrtf(ps1), EPSF) * fmaxf(sqrtf(nq1b), EPSF));
      out[(size_t)(2 + dir) * AS + base + 0] = m2av / fmaxf(sqrtf(ps2), EPSF);
      out[(size_t)(2 + dir) * AS + base + 1] = m2bv / fmaxf(sqrtf(ps3), EPSF);
      out[(size_t)(4 + dir) * AS + base + 0] =
          sg * m3n0 / (fmaxf(sqrtf(ps4), EPSF) * fmaxf(sqrtf(nh0), EPSF));
      out[(size_t)(4 + dir) * AS + base + 1] =
          sg * m3n1 / (fmaxf(sqrtf(ps5), EPSF) * fmaxf(sqrtf(nh1), EPSF));
      out[(size_t)(6 + dir) * AS + base + 0] =
          m4n0 / (fmaxf(sqrtf(ps6), EPSF) * fmaxf(sqrtf(nq4a), EPSF));
      out[(size_t)(6 + dir) * AS + base + 1] =
          m4n1 / (fmaxf(sqrtf(ps7), EPSF) * fmaxf(sqrtf(nq4b), EPSF));
    }
  }
}

extern "C" void kernel_launch(void* const* d_in, const int* in_sizes, int n_in,
                              void* d_out, int out_size, void* d_ws, size_t ws_size,
                              hipStream_t stream) {
  const float* pf  = (const float*)d_in[0];
  const float* pb  = (const float*)d_in[1];
  const float* qf  = (const float*)d_in[2];
  const float* qb  = (const float*)d_in[3];
  const float* w1f = (const float*)d_in[4];
  const float* w1b = (const float*)d_in[5];
  const float* w2f = (const float*)d_in[6];
  const float* w2b = (const float*)d_in[7];
  const float* w3f = (const float*)d_in[8];
  const float* w4f = (const float*)d_in[10];  // w3b/w4b unused by reference
  float* out = (float*)d_out;

  const size_t nq2_b  = (size_t)6 * BB * SS * 4;            //    589,824
  const size_t qhj_b  = (size_t)2 * HP * BB * SS * 2;       // 11,010,048 each
  float*    nq2    = (float*)d_ws;
  ushort_t* qhj_hi = (ushort_t*)((char*)d_ws + nq2_b);
  ushort_t* qhj_lo = (ushort_t*)((char*)d_ws + nq2_b + qhj_b);
  ushort_t* qTil   = (ushort_t*)((char*)d_ws + nq2_b + 2 * qhj_b);  // 26,738,688 B

  hipLaunchKernelGGL(qprep_kernel, dim3(2 * BB * 6), dim3(256), 0, stream,
                     qf, qb, w2f, w2b, nq2, qhj_hi, qhj_lo, qTil);
  hipLaunchKernelGGL(bimpm_fused, dim3(2 * BB * 6), dim3(256), 0, stream,
                     pf, pb, qf, qb, w1f, w1b, w2f, w2b, w3f, w4f,
                     nq2, qhj_hi, qhj_lo, qTil, out);
}